// Round 3
// baseline (943.598 us; speedup 1.0000x reference)
//
#include <hip/hip_runtime.h>

#define F_IN 128
#define F_H 64
#define F_OUT 16
#define RB 128           // nodes per bucket
#define RB_SHIFT 7       // bucket = dst >> 7
#define ACC_STRIDE 66    // f32 row stride of agg64 LDS acc (bank spread: gcd(66,32)=2)
#define ACC16_STRIDE 17  // f32 row stride of agg16 LDS acc (gcd(17,32)=1)

typedef unsigned long long u64;
typedef unsigned int u32;

__device__ __forceinline__ u32 pack2bf16(float a, float b) {
    // round-to-nearest via +0x8000 on the raw bits
    u32 ua = (__float_as_uint(a) + 0x8000u) >> 16;
    u32 ub = (__float_as_uint(b) + 0x8000u) & 0xFFFF0000u;
    return ua | ub;
}

// ---------------------------------------------------------------------------
// GEMM1: h1[N,64](bf16) = x[N,128] @ W1[128,64]
// ---------------------------------------------------------------------------
__global__ __launch_bounds__(256) void gemm1_kernel(
    const float* __restrict__ x, const float* __restrict__ W,
    u32* __restrict__ h1b, int N) {
    __shared__ float Wlds[64 * 64];
    __shared__ float Xlds[64][69];

    const int tid = threadIdx.x;
    const int n0 = blockIdx.x * 64;
    const int tf = tid & 15;
    const int tn = tid >> 4;

    float acc[4][4] = {{0.f, 0.f, 0.f, 0.f}, {0.f, 0.f, 0.f, 0.f},
                       {0.f, 0.f, 0.f, 0.f}, {0.f, 0.f, 0.f, 0.f}};

    for (int p = 0; p < 2; ++p) {
        for (int i = tid; i < 1024; i += 256) {
            const int kk = i >> 4, c4 = i & 15;
            float4 v = *(const float4*)(W + (size_t)(64 * p + kk) * 64 + 4 * c4);
            *(float4*)(&Wlds[kk * 64 + 4 * c4]) = v;
        }
        for (int i = tid; i < 1024; i += 256) {
            const int row = i >> 4, c4 = i & 15;
            int n = n0 + row;
            if (n >= N) n = N - 1;
            float4 v = *(const float4*)(x + (size_t)n * F_IN + 64 * p + 4 * c4);
            Xlds[row][4 * c4 + 0] = v.x;
            Xlds[row][4 * c4 + 1] = v.y;
            Xlds[row][4 * c4 + 2] = v.z;
            Xlds[row][4 * c4 + 3] = v.w;
        }
        __syncthreads();

        #pragma unroll 4
        for (int kk = 0; kk < 64; ++kk) {
            float4 w4 = *(const float4*)(&Wlds[kk * 64 + 4 * tf]);
            float xv[4];
            #pragma unroll
            for (int i2 = 0; i2 < 4; ++i2) xv[i2] = Xlds[4 * tn + i2][kk];
            #pragma unroll
            for (int i2 = 0; i2 < 4; ++i2) {
                acc[i2][0] += xv[i2] * w4.x;
                acc[i2][1] += xv[i2] * w4.y;
                acc[i2][2] += xv[i2] * w4.z;
                acc[i2][3] += xv[i2] * w4.w;
            }
        }
        __syncthreads();
    }

    #pragma unroll
    for (int i2 = 0; i2 < 4; ++i2) {
        const int n = n0 + 4 * tn + i2;
        if (n < N) {
            uint2 o = make_uint2(pack2bf16(acc[i2][0], acc[i2][1]),
                                 pack2bf16(acc[i2][2], acc[i2][3]));
            *(uint2*)(h1b + (size_t)n * 32 + tf * 2) = o;   // row = 32 u32 (128B)
        }
    }
}

// ---------------------------------------------------------------------------
// bucket histogram (LDS-staged)
// ---------------------------------------------------------------------------
__global__ __launch_bounds__(256) void hist_kernel(
    const int* __restrict__ dst, int* __restrict__ hist, int E, int nbuck) {
    __shared__ int h[800];
    for (int i = threadIdx.x; i < nbuck; i += 256) h[i] = 0;
    __syncthreads();
    for (int e = blockIdx.x * 256 + threadIdx.x; e < E; e += gridDim.x * 256)
        atomicAdd(&h[dst[e] >> RB_SHIFT], 1);
    __syncthreads();
    for (int i = threadIdx.x; i < nbuck; i += 256)
        if (h[i]) atomicAdd(&hist[i], h[i]);
}

// ---------------------------------------------------------------------------
// exclusive scan of bucket counts (single block; nbuck <= 1024)
// ---------------------------------------------------------------------------
__global__ __launch_bounds__(1024) void scan_kernel(
    const int* __restrict__ hist, int* __restrict__ gofs, int* __restrict__ gcur,
    int nbuck, int E) {
    __shared__ int s[1024];
    const int t = threadIdx.x;
    const int v = (t < nbuck) ? hist[t] : 0;
    s[t] = v;
    __syncthreads();
    for (int o = 1; o < 1024; o <<= 1) {
        int a = (t >= o) ? s[t - o] : 0;
        __syncthreads();
        s[t] += a;
        __syncthreads();
    }
    if (t < nbuck) {
        const int ex = s[t] - v;
        gofs[t] = ex;
        gcur[t] = ex;
    }
    if (t == 0) gofs[nbuck] = E;
}

// ---------------------------------------------------------------------------
// fill: block-local counting sort into bucket-grouped edata
// entry: [63:32]=weight f32 bits, [26:20]=dst&127, [16:0]=src
// ---------------------------------------------------------------------------
__global__ __launch_bounds__(256) void fill_kernel(
    const int* __restrict__ src, const int* __restrict__ dst,
    const float* __restrict__ ew, int* __restrict__ gcur,
    u64* __restrict__ edata, int E, int nbuck) {
    __shared__ int cnt[800];
    __shared__ int base[800];
    const int chunk = (E + gridDim.x - 1) / gridDim.x;
    const int e0 = blockIdx.x * chunk;
    const int e1 = min(e0 + chunk, E);

    for (int i = threadIdx.x; i < nbuck; i += 256) cnt[i] = 0;
    __syncthreads();
    for (int e = e0 + threadIdx.x; e < e1; e += 256)
        atomicAdd(&cnt[dst[e] >> RB_SHIFT], 1);
    __syncthreads();
    for (int i = threadIdx.x; i < nbuck; i += 256) {
        const int c = cnt[i];
        base[i] = c ? atomicAdd(&gcur[i], c) : 0;
        cnt[i] = 0;                          // becomes local cursor
    }
    __syncthreads();
    for (int e = e0 + threadIdx.x; e < e1; e += 256) {
        const int d = dst[e];
        const int b = d >> RB_SHIFT;
        const int p = atomicAdd(&cnt[b], 1);
        const u32 lo = (u32)src[e] | ((u32)(d & (RB - 1)) << 20);
        const u64 packed = ((u64)__float_as_uint(ew[e]) << 32) | lo;
        edata[(size_t)base[b] + p] = packed;
    }
}

// ---------------------------------------------------------------------------
// agg64 + relu + W2 fused: one block per bucket.
//   acc = segment_sum over bucket of w * h1[src]  (LDS f32 atomics)
//   h2[node] = relu(acc + b1) @ W2               (mini-GEMM in LDS)
// ---------------------------------------------------------------------------
__global__ __launch_bounds__(256) void agg64_kernel(
    const u32* __restrict__ h1b, const u64* __restrict__ edata,
    const int* __restrict__ gofs, const float* __restrict__ b1,
    const float* __restrict__ W2, float* __restrict__ h2, int N) {
    __shared__ float acc[RB * ACC_STRIDE];   // 33792 B
    __shared__ float w2l[64 * 16];           // 4096 B
    __shared__ float b1l[64];

    const int tid = threadIdx.x;
    for (int i = tid; i < RB * ACC_STRIDE; i += 256) acc[i] = 0.f;
    for (int i = tid; i < 1024; i += 256) w2l[i] = W2[i];
    if (tid < 64) b1l[tid] = b1[tid];
    __syncthreads();

    const int bstart = gofs[blockIdx.x];
    const int bend = gofs[blockIdx.x + 1];
    const int f4 = tid & 15;                 // 4 floats (8B of bf16) per lane
    const int eslot = tid >> 4;              // 16 edges in flight per block

    int i = bstart + eslot;
    for (; i + 16 < bend; i += 32) {         // unroll 2
        const u64 ed0 = edata[i];
        const u64 ed1 = edata[i + 16];
        const u32 lo0 = (u32)ed0, lo1 = (u32)ed1;
        const float w0 = __uint_as_float((u32)(ed0 >> 32));
        const float w1 = __uint_as_float((u32)(ed1 >> 32));
        const int s0 = lo0 & 0xFFFFF, s1 = lo1 & 0xFFFFF;
        const int d0 = lo0 >> 20, d1 = lo1 >> 20;
        const uint2 v0 = *(const uint2*)(h1b + (size_t)s0 * 32 + f4 * 2);
        const uint2 v1 = *(const uint2*)(h1b + (size_t)s1 * 32 + f4 * 2);
        float* a0 = &acc[d0 * ACC_STRIDE + f4 * 4];
        float* a1 = &acc[d1 * ACC_STRIDE + f4 * 4];
        atomicAdd(a0 + 0, __uint_as_float(v0.x << 16) * w0);
        atomicAdd(a0 + 1, __uint_as_float(v0.x & 0xFFFF0000u) * w0);
        atomicAdd(a0 + 2, __uint_as_float(v0.y << 16) * w0);
        atomicAdd(a0 + 3, __uint_as_float(v0.y & 0xFFFF0000u) * w0);
        atomicAdd(a1 + 0, __uint_as_float(v1.x << 16) * w1);
        atomicAdd(a1 + 1, __uint_as_float(v1.x & 0xFFFF0000u) * w1);
        atomicAdd(a1 + 2, __uint_as_float(v1.y << 16) * w1);
        atomicAdd(a1 + 3, __uint_as_float(v1.y & 0xFFFF0000u) * w1);
    }
    if (i < bend) {
        const u64 ed0 = edata[i];
        const u32 lo0 = (u32)ed0;
        const float w0 = __uint_as_float((u32)(ed0 >> 32));
        const int s0 = lo0 & 0xFFFFF;
        const int d0 = lo0 >> 20;
        const uint2 v0 = *(const uint2*)(h1b + (size_t)s0 * 32 + f4 * 2);
        float* a0 = &acc[d0 * ACC_STRIDE + f4 * 4];
        atomicAdd(a0 + 0, __uint_as_float(v0.x << 16) * w0);
        atomicAdd(a0 + 1, __uint_as_float(v0.x & 0xFFFF0000u) * w0);
        atomicAdd(a0 + 2, __uint_as_float(v0.y << 16) * w0);
        atomicAdd(a0 + 3, __uint_as_float(v0.y & 0xFFFF0000u) * w0);
    }
    __syncthreads();

    // mini-GEMM: h2[node][0:16] = relu(acc[node]+b1) @ W2
    const int node = tid >> 1;
    const int half = tid & 1;
    const int gnode = blockIdx.x * RB + node;
    if (gnode < N) {
        float o[8] = {0.f, 0.f, 0.f, 0.f, 0.f, 0.f, 0.f, 0.f};
        const float* ar = &acc[node * ACC_STRIDE];
        #pragma unroll 8
        for (int k = 0; k < 64; ++k) {
            const float t = fmaxf(ar[k] + b1l[k], 0.f);
            const float* wr = &w2l[k * 16 + half * 8];
            #pragma unroll
            for (int j = 0; j < 8; ++j) o[j] += t * wr[j];
        }
        float4* o4 = (float4*)(h2 + (size_t)gnode * 16 + half * 8);
        o4[0] = make_float4(o[0], o[1], o[2], o[3]);
        o4[1] = make_float4(o[4], o[5], o[6], o[7]);
    }
}

// ---------------------------------------------------------------------------
// agg16: out[node] = b2 + segment_sum over bucket of w * h2[src]
// ---------------------------------------------------------------------------
__global__ __launch_bounds__(256) void agg16_kernel(
    const float* __restrict__ h2, const u64* __restrict__ edata,
    const int* __restrict__ gofs, const float* __restrict__ b2,
    float* __restrict__ out, int N) {
    __shared__ float acc[RB * ACC16_STRIDE];  // 8704 B

    const int tid = threadIdx.x;
    for (int i = tid; i < RB * ACC16_STRIDE; i += 256) acc[i] = 0.f;
    __syncthreads();

    const int bstart = gofs[blockIdx.x];
    const int bend = gofs[blockIdx.x + 1];
    const int f4 = tid & 3;                  // float4 per lane
    const int eslot = tid >> 2;              // 64 edges in flight

    int i = bstart + eslot;
    for (; i + 64 < bend; i += 128) {        // unroll 2
        const u64 ed0 = edata[i];
        const u64 ed1 = edata[i + 64];
        const u32 lo0 = (u32)ed0, lo1 = (u32)ed1;
        const float w0 = __uint_as_float((u32)(ed0 >> 32));
        const float w1 = __uint_as_float((u32)(ed1 >> 32));
        const int s0 = lo0 & 0xFFFFF, s1 = lo1 & 0xFFFFF;
        const int d0 = lo0 >> 20, d1 = lo1 >> 20;
        const float4 v0 = *(const float4*)(h2 + (size_t)s0 * 16 + f4 * 4);
        const float4 v1 = *(const float4*)(h2 + (size_t)s1 * 16 + f4 * 4);
        float* a0 = &acc[d0 * ACC16_STRIDE + f4 * 4];
        float* a1 = &acc[d1 * ACC16_STRIDE + f4 * 4];
        atomicAdd(a0 + 0, v0.x * w0);
        atomicAdd(a0 + 1, v0.y * w0);
        atomicAdd(a0 + 2, v0.z * w0);
        atomicAdd(a0 + 3, v0.w * w0);
        atomicAdd(a1 + 0, v1.x * w1);
        atomicAdd(a1 + 1, v1.y * w1);
        atomicAdd(a1 + 2, v1.z * w1);
        atomicAdd(a1 + 3, v1.w * w1);
    }
    if (i < bend) {
        const u64 ed0 = edata[i];
        const u32 lo0 = (u32)ed0;
        const float w0 = __uint_as_float((u32)(ed0 >> 32));
        const int s0 = lo0 & 0xFFFFF;
        const int d0 = lo0 >> 20;
        const float4 v0 = *(const float4*)(h2 + (size_t)s0 * 16 + f4 * 4);
        float* a0 = &acc[d0 * ACC16_STRIDE + f4 * 4];
        atomicAdd(a0 + 0, v0.x * w0);
        atomicAdd(a0 + 1, v0.y * w0);
        atomicAdd(a0 + 2, v0.z * w0);
        atomicAdd(a0 + 3, v0.w * w0);
    }
    __syncthreads();

    for (int i2 = tid; i2 < RB * 4; i2 += 256) {
        const int node = i2 >> 2, q = i2 & 3;
        const int gnode = blockIdx.x * RB + node;
        if (gnode < N) {
            const float4 bv = ((const float4*)b2)[q];
            const float* ar = &acc[node * ACC16_STRIDE + q * 4];
            *(float4*)(out + (size_t)gnode * 16 + q * 4) =
                make_float4(ar[0] + bv.x, ar[1] + bv.y, ar[2] + bv.z, ar[3] + bv.w);
        }
    }
}

extern "C" void kernel_launch(void* const* d_in, const int* in_sizes, int n_in,
                              void* d_out, int out_size, void* d_ws, size_t ws_size,
                              hipStream_t stream) {
    const float* x   = (const float*)d_in[0];
    const int*   src = (const int*)d_in[1];
    const int*   dst = (const int*)d_in[2];
    const float* ew  = (const float*)d_in[3];
    const float* W1  = (const float*)d_in[4];
    const float* b1  = (const float*)d_in[5];
    const float* W2  = (const float*)d_in[6];
    const float* b2  = (const float*)d_in[7];
    float* out = (float*)d_out;

    const int N = in_sizes[0] / F_IN;        // 100000
    const int E = in_sizes[1];               // 1600000
    const int nbuck = (N + RB - 1) >> RB_SHIFT;  // 782

    char* base = (char*)d_ws;
    auto align256 = [](size_t v) { return (v + 255) & ~(size_t)255; };
    size_t oH1   = 0;
    size_t oH2   = align256(oH1 + (size_t)N * 32 * 4);       // h1 bf16: 12.8 MB
    size_t oED   = align256(oH2 + (size_t)N * F_OUT * 4);    // h2 f32:   6.4 MB
    size_t oHIST = align256(oED + (size_t)E * 8);            // edata:   12.8 MB
    size_t oOFS  = align256(oHIST + (size_t)nbuck * 4);
    size_t oCUR  = align256(oOFS + (size_t)(nbuck + 1) * 4);

    u32*   h1b   = (u32*)(base + oH1);
    float* h2    = (float*)(base + oH2);
    u64*   edata = (u64*)(base + oED);
    int*   hist  = (int*)(base + oHIST);
    int*   gofs  = (int*)(base + oOFS);
    int*   gcur  = (int*)(base + oCUR);

    // bucket build
    hipMemsetAsync(hist, 0, (size_t)nbuck * 4, stream);
    hist_kernel<<<512, 256, 0, stream>>>(dst, hist, E, nbuck);
    scan_kernel<<<1, 1024, 0, stream>>>(hist, gofs, gcur, nbuck, E);
    fill_kernel<<<256, 256, 0, stream>>>(src, dst, ew, gcur, edata, E, nbuck);

    // layer 1 transform
    gemm1_kernel<<<(N + 63) / 64, 256, 0, stream>>>(x, W1, h1b, N);
    // layer-1 aggregate + relu + W2 transform (fused)
    agg64_kernel<<<nbuck, 256, 0, stream>>>(h1b, edata, gofs, b1, W2, h2, N);
    // layer-2 aggregate + bias
    agg16_kernel<<<nbuck, 256, 0, stream>>>(h2, edata, gofs, b2, out, N);
}

// Round 4
// 189.129 us; speedup vs baseline: 4.9892x; 4.9892x over previous
//
#include <hip/hip_runtime.h>

#define F_IN 128
#define F_H 64
#define F_OUT 16
#define RB 128           // nodes per bucket
#define RB_SHIFT 7       // bucket = dst >> 7

typedef unsigned long long u64;
typedef unsigned int u32;

__device__ __forceinline__ u32 pack2bf16(float a, float b) {
    u32 ua = (__float_as_uint(a) + 0x8000u) >> 16;
    u32 ub = (__float_as_uint(b) + 0x8000u) & 0xFFFF0000u;
    return ua | ub;
}

// ---------------------------------------------------------------------------
// GEMM1: h1[N,64](bf16 packed in u32 pairs) = x[N,128] @ W1[128,64]
// ---------------------------------------------------------------------------
__global__ __launch_bounds__(256) void gemm1_kernel(
    const float* __restrict__ x, const float* __restrict__ W,
    u32* __restrict__ h1b, int N) {
    __shared__ float Wlds[64 * 64];
    __shared__ float Xlds[64][69];

    const int tid = threadIdx.x;
    const int n0 = blockIdx.x * 64;
    const int tf = tid & 15;
    const int tn = tid >> 4;

    float acc[4][4] = {{0.f, 0.f, 0.f, 0.f}, {0.f, 0.f, 0.f, 0.f},
                       {0.f, 0.f, 0.f, 0.f}, {0.f, 0.f, 0.f, 0.f}};

    for (int p = 0; p < 2; ++p) {
        for (int i = tid; i < 1024; i += 256) {
            const int kk = i >> 4, c4 = i & 15;
            float4 v = *(const float4*)(W + (size_t)(64 * p + kk) * 64 + 4 * c4);
            *(float4*)(&Wlds[kk * 64 + 4 * c4]) = v;
        }
        for (int i = tid; i < 1024; i += 256) {
            const int row = i >> 4, c4 = i & 15;
            int n = n0 + row;
            if (n >= N) n = N - 1;
            float4 v = *(const float4*)(x + (size_t)n * F_IN + 64 * p + 4 * c4);
            Xlds[row][4 * c4 + 0] = v.x;
            Xlds[row][4 * c4 + 1] = v.y;
            Xlds[row][4 * c4 + 2] = v.z;
            Xlds[row][4 * c4 + 3] = v.w;
        }
        __syncthreads();

        #pragma unroll 4
        for (int kk = 0; kk < 64; ++kk) {
            float4 w4 = *(const float4*)(&Wlds[kk * 64 + 4 * tf]);
            float xv[4];
            #pragma unroll
            for (int i2 = 0; i2 < 4; ++i2) xv[i2] = Xlds[4 * tn + i2][kk];
            #pragma unroll
            for (int i2 = 0; i2 < 4; ++i2) {
                acc[i2][0] += xv[i2] * w4.x;
                acc[i2][1] += xv[i2] * w4.y;
                acc[i2][2] += xv[i2] * w4.z;
                acc[i2][3] += xv[i2] * w4.w;
            }
        }
        __syncthreads();
    }

    #pragma unroll
    for (int i2 = 0; i2 < 4; ++i2) {
        const int n = n0 + 4 * tn + i2;
        if (n < N) {
            uint2 o = make_uint2(pack2bf16(acc[i2][0], acc[i2][1]),
                                 pack2bf16(acc[i2][2], acc[i2][3]));
            *(uint2*)(h1b + (size_t)n * 32 + tf * 2) = o;   // feats 4*tf..4*tf+3
        }
    }
}

// ---------------------------------------------------------------------------
// bucket histogram (LDS-staged)
// ---------------------------------------------------------------------------
__global__ __launch_bounds__(256) void hist_kernel(
    const int* __restrict__ dst, int* __restrict__ hist, int E, int nbuck) {
    __shared__ int h[800];
    for (int i = threadIdx.x; i < nbuck; i += 256) h[i] = 0;
    __syncthreads();
    for (int e = blockIdx.x * 256 + threadIdx.x; e < E; e += gridDim.x * 256)
        atomicAdd(&h[dst[e] >> RB_SHIFT], 1);
    __syncthreads();
    for (int i = threadIdx.x; i < nbuck; i += 256)
        if (h[i]) atomicAdd(&hist[i], h[i]);
}

// ---------------------------------------------------------------------------
// exclusive scan of bucket counts (single block; nbuck <= 1024)
// ---------------------------------------------------------------------------
__global__ __launch_bounds__(1024) void scan_kernel(
    const int* __restrict__ hist, int* __restrict__ gofs, int* __restrict__ gcur,
    int nbuck, int E) {
    __shared__ int s[1024];
    const int t = threadIdx.x;
    const int v = (t < nbuck) ? hist[t] : 0;
    s[t] = v;
    __syncthreads();
    for (int o = 1; o < 1024; o <<= 1) {
        int a = (t >= o) ? s[t - o] : 0;
        __syncthreads();
        s[t] += a;
        __syncthreads();
    }
    if (t < nbuck) {
        const int ex = s[t] - v;
        gofs[t] = ex;
        gcur[t] = ex;
    }
    if (t == 0) gofs[nbuck] = E;
}

// ---------------------------------------------------------------------------
// fill: block-local counting sort into bucket-grouped edata1
// entry: [63:32]=weight f32 bits, [26:20]=dst&127, [19:0]=src
// ---------------------------------------------------------------------------
__global__ __launch_bounds__(256) void fill_kernel(
    const int* __restrict__ src, const int* __restrict__ dst,
    const float* __restrict__ ew, int* __restrict__ gcur,
    u64* __restrict__ edata, int E, int nbuck) {
    __shared__ int cnt[800];
    __shared__ int base[800];
    const int chunk = (E + gridDim.x - 1) / gridDim.x;
    const int e0 = blockIdx.x * chunk;
    const int e1 = min(e0 + chunk, E);

    for (int i = threadIdx.x; i < nbuck; i += 256) cnt[i] = 0;
    __syncthreads();
    for (int e = e0 + threadIdx.x; e < e1; e += 256)
        atomicAdd(&cnt[dst[e] >> RB_SHIFT], 1);
    __syncthreads();
    for (int i = threadIdx.x; i < nbuck; i += 256) {
        const int c = cnt[i];
        base[i] = c ? atomicAdd(&gcur[i], c) : 0;
        cnt[i] = 0;                          // becomes local cursor
    }
    __syncthreads();
    for (int e = e0 + threadIdx.x; e < e1; e += 256) {
        const int d = dst[e];
        const int b = d >> RB_SHIFT;
        const int p = atomicAdd(&cnt[b], 1);
        const u32 lo = (u32)src[e] | ((u32)(d & (RB - 1)) << 20);
        const u64 packed = ((u64)__float_as_uint(ew[e]) << 32) | lo;
        edata[(size_t)base[b] + p] = packed;
    }
}

// ---------------------------------------------------------------------------
// sort: one block per bucket. Counting-sort the bucket's edges by local dst
// node -> per-node-sorted edata2 (contiguous coalesced-ish 16KB range) +
// global rowptr.
// ---------------------------------------------------------------------------
__global__ __launch_bounds__(256) void sort_kernel(
    const u64* __restrict__ edata1, const int* __restrict__ gofs,
    u64* __restrict__ edata2, int* __restrict__ rowptr, int N, int E) {
    __shared__ int cnt[RB];
    __shared__ int pref[RB];
    __shared__ int cur[RB];
    const int tid = threadIdx.x;
    const int b = blockIdx.x;
    const int s0 = gofs[b], s1 = gofs[b + 1];

    if (tid < RB) cnt[tid] = 0;
    __syncthreads();
    for (int i = s0 + tid; i < s1; i += 256) {
        const int d = ((u32)edata1[i] >> 20) & (RB - 1);
        atomicAdd(&cnt[d], 1);
    }
    __syncthreads();
    if (tid < RB) pref[tid] = cnt[tid];
    __syncthreads();
    for (int o = 1; o < RB; o <<= 1) {
        int v = 0;
        if (tid < RB && tid >= o) v = pref[tid - o];
        __syncthreads();
        if (tid < RB) pref[tid] += v;
        __syncthreads();
    }
    if (tid < RB) {
        const int ex = pref[tid] - cnt[tid];   // exclusive prefix
        cur[tid] = ex;
        const int gn = b * RB + tid;
        if (gn < N) rowptr[gn] = s0 + ex;
    }
    if (b == 0 && tid == 0) rowptr[N] = E;
    __syncthreads();
    for (int i = s0 + tid; i < s1; i += 256) {
        const u64 ed = edata1[i];
        const int d = ((u32)ed >> 20) & (RB - 1);
        const int p = atomicAdd(&cur[d], 1);
        edata2[(size_t)s0 + p] = ed;
    }
}

// ---------------------------------------------------------------------------
// agg64: agg[n] = b1 + sum_{e in rows[n]} w_e * h1[src_e]  (16 lanes/node,
// register accumulation, bf16 gathers)
// ---------------------------------------------------------------------------
__global__ __launch_bounds__(256) void agg64_kernel(
    const u32* __restrict__ h1b, const u64* __restrict__ edata,
    const int* __restrict__ rowptr, const float* __restrict__ bias,
    float* __restrict__ agg, int N) {
    const int tid = threadIdx.x;
    const int n = blockIdx.x * 16 + (tid >> 4);
    const int f4 = tid & 15;
    if (n >= N) return;

    float4 acc = *(const float4*)(bias + 4 * f4);
    int i = rowptr[n];
    const int end = rowptr[n + 1];

    for (; i + 1 < end; i += 2) {
        const u64 e0 = edata[i], e1 = edata[i + 1];
        const int s0 = (u32)e0 & 0xFFFFF, s1 = (u32)e1 & 0xFFFFF;
        const float w0 = __uint_as_float((u32)(e0 >> 32));
        const float w1 = __uint_as_float((u32)(e1 >> 32));
        const uint2 v0 = *(const uint2*)(h1b + (size_t)s0 * 32 + f4 * 2);
        const uint2 v1 = *(const uint2*)(h1b + (size_t)s1 * 32 + f4 * 2);
        acc.x += __uint_as_float(v0.x << 16) * w0 + __uint_as_float(v1.x << 16) * w1;
        acc.y += __uint_as_float(v0.x & 0xFFFF0000u) * w0 + __uint_as_float(v1.x & 0xFFFF0000u) * w1;
        acc.z += __uint_as_float(v0.y << 16) * w0 + __uint_as_float(v1.y << 16) * w1;
        acc.w += __uint_as_float(v0.y & 0xFFFF0000u) * w0 + __uint_as_float(v1.y & 0xFFFF0000u) * w1;
    }
    if (i < end) {
        const u64 e0 = edata[i];
        const int s0 = (u32)e0 & 0xFFFFF;
        const float w0 = __uint_as_float((u32)(e0 >> 32));
        const uint2 v0 = *(const uint2*)(h1b + (size_t)s0 * 32 + f4 * 2);
        acc.x += __uint_as_float(v0.x << 16) * w0;
        acc.y += __uint_as_float(v0.x & 0xFFFF0000u) * w0;
        acc.z += __uint_as_float(v0.y << 16) * w0;
        acc.w += __uint_as_float(v0.y & 0xFFFF0000u) * w0;
    }
    *(float4*)(agg + (size_t)n * F_H + 4 * f4) = acc;
}

// ---------------------------------------------------------------------------
// GEMM2: h2[N,16] = relu(agg1[N,64]) @ W2[64,16]  (relu fused into LDS load)
// ---------------------------------------------------------------------------
__global__ __launch_bounds__(256) void gemm2_kernel(
    const float* __restrict__ agg1, const float* __restrict__ W2,
    float* __restrict__ h2, int N) {
    __shared__ float Wlds[64 * 16];
    __shared__ float Xlds[64][65];

    const int tid = threadIdx.x;
    const int n0 = blockIdx.x * 64;

    {
        float4 v = ((const float4*)W2)[tid];
        ((float4*)Wlds)[tid] = v;
    }
    for (int i = tid; i < 64 * 16; i += 256) {
        const int row = i >> 4, c4 = i & 15;
        int n = n0 + row;
        if (n >= N) n = N - 1;
        float4 v = *(const float4*)(agg1 + (size_t)n * F_H + 4 * c4);
        Xlds[row][4 * c4 + 0] = fmaxf(v.x, 0.f);
        Xlds[row][4 * c4 + 1] = fmaxf(v.y, 0.f);
        Xlds[row][4 * c4 + 2] = fmaxf(v.z, 0.f);
        Xlds[row][4 * c4 + 3] = fmaxf(v.w, 0.f);
    }
    __syncthreads();

    const int tf4 = tid & 3;
    const int tn = tid >> 2;
    float a0 = 0.f, a1 = 0.f, a2 = 0.f, a3 = 0.f;
    #pragma unroll 8
    for (int k = 0; k < 64; ++k) {
        const float xv = Xlds[tn][k];
        float4 w4 = *(const float4*)(&Wlds[k * 16 + 4 * tf4]);
        a0 += xv * w4.x;
        a1 += xv * w4.y;
        a2 += xv * w4.z;
        a3 += xv * w4.w;
    }
    const int n = n0 + tn;
    if (n < N) {
        *(float4*)(h2 + (size_t)n * F_OUT + 4 * tf4) = make_float4(a0, a1, a2, a3);
    }
}

// ---------------------------------------------------------------------------
// agg16: out[n] = b2 + sum w_e * h2[src_e]   (4 lanes/node, register acc)
// ---------------------------------------------------------------------------
__global__ __launch_bounds__(256) void agg16_kernel(
    const float* __restrict__ h2, const u64* __restrict__ edata,
    const int* __restrict__ rowptr, const float* __restrict__ b2,
    float* __restrict__ out, int N) {
    const int tid = threadIdx.x;
    const int n = blockIdx.x * 64 + (tid >> 2);
    const int f4 = tid & 3;
    if (n >= N) return;

    float4 acc = ((const float4*)b2)[f4];
    int i = rowptr[n];
    const int end = rowptr[n + 1];

    for (; i + 1 < end; i += 2) {
        const u64 e0 = edata[i], e1 = edata[i + 1];
        const int s0 = (u32)e0 & 0xFFFFF, s1 = (u32)e1 & 0xFFFFF;
        const float w0 = __uint_as_float((u32)(e0 >> 32));
        const float w1 = __uint_as_float((u32)(e1 >> 32));
        const float4 v0 = *(const float4*)(h2 + (size_t)s0 * F_OUT + 4 * f4);
        const float4 v1 = *(const float4*)(h2 + (size_t)s1 * F_OUT + 4 * f4);
        acc.x += v0.x * w0 + v1.x * w1;
        acc.y += v0.y * w0 + v1.y * w1;
        acc.z += v0.z * w0 + v1.z * w1;
        acc.w += v0.w * w0 + v1.w * w1;
    }
    if (i < end) {
        const u64 e0 = edata[i];
        const int s0 = (u32)e0 & 0xFFFFF;
        const float w0 = __uint_as_float((u32)(e0 >> 32));
        const float4 v0 = *(const float4*)(h2 + (size_t)s0 * F_OUT + 4 * f4);
        acc.x += v0.x * w0;
        acc.y += v0.y * w0;
        acc.z += v0.z * w0;
        acc.w += v0.w * w0;
    }
    *(float4*)(out + (size_t)n * F_OUT + 4 * f4) = acc;
}

extern "C" void kernel_launch(void* const* d_in, const int* in_sizes, int n_in,
                              void* d_out, int out_size, void* d_ws, size_t ws_size,
                              hipStream_t stream) {
    const float* x   = (const float*)d_in[0];
    const int*   src = (const int*)d_in[1];
    const int*   dst = (const int*)d_in[2];
    const float* ew  = (const float*)d_in[3];
    const float* W1  = (const float*)d_in[4];
    const float* b1  = (const float*)d_in[5];
    const float* W2  = (const float*)d_in[6];
    const float* b2  = (const float*)d_in[7];
    float* out = (float*)d_out;

    const int N = in_sizes[0] / F_IN;            // 100000
    const int E = in_sizes[1];                   // 1600000
    const int nbuck = (N + RB - 1) >> RB_SHIFT;  // 782

    char* base = (char*)d_ws;
    auto align256 = [](size_t v) { return (v + 255) & ~(size_t)255; };
    // R0: h1b (bf16, 12.8MB), later reused by h2 (6.4MB)
    // R1: edata1 (12.8MB), later reused by agg1 (25.6MB)
    // R2: edata2 (12.8MB, live through agg16)
    size_t oR0   = 0;
    size_t oR1   = align256(oR0 + (size_t)N * 32 * 4);
    size_t oR2   = align256(oR1 + (size_t)N * F_H * 4);
    size_t oROW  = align256(oR2 + (size_t)E * 8);
    size_t oHIST = align256(oROW + (size_t)(N + 1) * 4);
    size_t oOFS  = align256(oHIST + (size_t)nbuck * 4);
    size_t oCUR  = align256(oOFS + (size_t)(nbuck + 1) * 4);
    (void)oCUR; (void)ws_size;

    u32*   h1b    = (u32*)(base + oR0);
    float* h2     = (float*)(base + oR0);
    u64*   edata1 = (u64*)(base + oR1);
    float* agg1   = (float*)(base + oR1);
    u64*   edata2 = (u64*)(base + oR2);
    int*   rowptr = (int*)(base + oROW);
    int*   hist   = (int*)(base + oHIST);
    int*   gofs   = (int*)(base + oOFS);
    int*   gcur   = (int*)(base + oCUR);

    // ---- graph preprocessing: bucket sort -> per-node sort
    hipMemsetAsync(hist, 0, (size_t)nbuck * 4, stream);
    hist_kernel<<<512, 256, 0, stream>>>(dst, hist, E, nbuck);
    scan_kernel<<<1, 1024, 0, stream>>>(hist, gofs, gcur, nbuck, E);
    fill_kernel<<<256, 256, 0, stream>>>(src, dst, ew, gcur, edata1, E, nbuck);
    sort_kernel<<<nbuck, 256, 0, stream>>>(edata1, gofs, edata2, rowptr, N, E);

    // ---- layer 1 (gemm1 is independent of preprocessing; edata1 region is
    //      only overwritten by agg64's agg1 output, after sort is done)
    gemm1_kernel<<<(N + 63) / 64, 256, 0, stream>>>(x, W1, h1b, N);
    agg64_kernel<<<(N + 15) / 16, 256, 0, stream>>>(h1b, edata2, rowptr, b1, agg1, N);

    // ---- layer 2
    gemm2_kernel<<<(N + 63) / 64, 256, 0, stream>>>(agg1, W2, h2, N);
    agg16_kernel<<<(N + 63) / 64, 256, 0, stream>>>(h2, edata2, rowptr, b2, out, N);
}

// Round 5
// 169.115 us; speedup vs baseline: 5.5796x; 1.1183x over previous
//
#include <hip/hip_runtime.h>

#define F_IN 128
#define F_H 64
#define F_OUT 16
#define RB 128           // nodes per bucket
#define RB_SHIFT 7       // bucket = dst >> 7

typedef unsigned long long u64;
typedef unsigned int u32;

__device__ __forceinline__ u32 pack2bf16(float a, float b) {
    u32 ua = (__float_as_uint(a) + 0x8000u) >> 16;
    u32 ub = (__float_as_uint(b) + 0x8000u) & 0xFFFF0000u;
    return ua | ub;
}

// ---------------------------------------------------------------------------
// GEMM1: h1[N,64](bf16 packed in u32 pairs) = x[N,128] @ W1[128,64]
// ---------------------------------------------------------------------------
__global__ __launch_bounds__(256) void gemm1_kernel(
    const float* __restrict__ x, const float* __restrict__ W,
    u32* __restrict__ h1b, int N) {
    __shared__ float Wlds[64 * 64];
    __shared__ float Xlds[64][69];

    const int tid = threadIdx.x;
    const int n0 = blockIdx.x * 64;
    const int tf = tid & 15;
    const int tn = tid >> 4;

    float acc[4][4] = {{0.f, 0.f, 0.f, 0.f}, {0.f, 0.f, 0.f, 0.f},
                       {0.f, 0.f, 0.f, 0.f}, {0.f, 0.f, 0.f, 0.f}};

    for (int p = 0; p < 2; ++p) {
        for (int i = tid; i < 1024; i += 256) {
            const int kk = i >> 4, c4 = i & 15;
            float4 v = *(const float4*)(W + (size_t)(64 * p + kk) * 64 + 4 * c4);
            *(float4*)(&Wlds[kk * 64 + 4 * c4]) = v;
        }
        for (int i = tid; i < 1024; i += 256) {
            const int row = i >> 4, c4 = i & 15;
            int n = n0 + row;
            if (n >= N) n = N - 1;
            float4 v = *(const float4*)(x + (size_t)n * F_IN + 64 * p + 4 * c4);
            Xlds[row][4 * c4 + 0] = v.x;
            Xlds[row][4 * c4 + 1] = v.y;
            Xlds[row][4 * c4 + 2] = v.z;
            Xlds[row][4 * c4 + 3] = v.w;
        }
        __syncthreads();

        #pragma unroll 4
        for (int kk = 0; kk < 64; ++kk) {
            float4 w4 = *(const float4*)(&Wlds[kk * 64 + 4 * tf]);
            float xv[4];
            #pragma unroll
            for (int i2 = 0; i2 < 4; ++i2) xv[i2] = Xlds[4 * tn + i2][kk];
            #pragma unroll
            for (int i2 = 0; i2 < 4; ++i2) {
                acc[i2][0] += xv[i2] * w4.x;
                acc[i2][1] += xv[i2] * w4.y;
                acc[i2][2] += xv[i2] * w4.z;
                acc[i2][3] += xv[i2] * w4.w;
            }
        }
        __syncthreads();
    }

    #pragma unroll
    for (int i2 = 0; i2 < 4; ++i2) {
        const int n = n0 + 4 * tn + i2;
        if (n < N) {
            uint2 o = make_uint2(pack2bf16(acc[i2][0], acc[i2][1]),
                                 pack2bf16(acc[i2][2], acc[i2][3]));
            *(uint2*)(h1b + (size_t)n * 32 + tf * 2) = o;   // feats 4*tf..4*tf+3
        }
    }
}

// ---------------------------------------------------------------------------
// bucket histogram (LDS-staged, int4 reads, 1024 threads)
// ---------------------------------------------------------------------------
__global__ __launch_bounds__(1024) void hist_kernel(
    const int* __restrict__ dst, int* __restrict__ hist, int E, int nbuck) {
    __shared__ int h[800];
    for (int i = threadIdx.x; i < nbuck; i += 1024) h[i] = 0;
    __syncthreads();
    const int nstep = gridDim.x * 1024;
    int e = (blockIdx.x * 1024 + threadIdx.x) * 4;
    for (; e + 3 < E; e += nstep * 4) {
        const int4 d4 = *(const int4*)(dst + e);
        atomicAdd(&h[d4.x >> RB_SHIFT], 1);
        atomicAdd(&h[d4.y >> RB_SHIFT], 1);
        atomicAdd(&h[d4.z >> RB_SHIFT], 1);
        atomicAdd(&h[d4.w >> RB_SHIFT], 1);
    }
    for (; e < E; ++e) atomicAdd(&h[dst[e] >> RB_SHIFT], 1);
    __syncthreads();
    for (int i = threadIdx.x; i < nbuck; i += 1024)
        if (h[i]) atomicAdd(&hist[i], h[i]);
}

// ---------------------------------------------------------------------------
// exclusive scan of bucket counts (single block; nbuck <= 1024)
// ---------------------------------------------------------------------------
__global__ __launch_bounds__(1024) void scan_kernel(
    const int* __restrict__ hist, int* __restrict__ gofs, int* __restrict__ gcur,
    int nbuck, int E) {
    __shared__ int s[1024];
    const int t = threadIdx.x;
    const int v = (t < nbuck) ? hist[t] : 0;
    s[t] = v;
    __syncthreads();
    for (int o = 1; o < 1024; o <<= 1) {
        int a = (t >= o) ? s[t - o] : 0;
        __syncthreads();
        s[t] += a;
        __syncthreads();
    }
    if (t < nbuck) {
        const int ex = s[t] - v;
        gofs[t] = ex;
        gcur[t] = ex;
    }
    if (t == 0) gofs[nbuck] = E;
}

// ---------------------------------------------------------------------------
// fill: block-local counting sort into bucket-grouped edata1 (1024 threads,
// 4 edges/thread/iter via vector loads)
// entry: [63:32]=weight f32 bits, [26:20]=dst&127, [19:0]=src
// ---------------------------------------------------------------------------
__global__ __launch_bounds__(1024) void fill_kernel(
    const int* __restrict__ src, const int* __restrict__ dst,
    const float* __restrict__ ew, int* __restrict__ gcur,
    u64* __restrict__ edata, int E, int nbuck) {
    __shared__ int cnt[800];
    __shared__ int base[800];
    int chunk = (E + gridDim.x - 1) / gridDim.x;
    chunk = (chunk + 3) & ~3;                       // keep e0 4-aligned
    const int e0 = blockIdx.x * chunk;
    const int e1 = min(e0 + chunk, E);

    for (int i = threadIdx.x; i < nbuck; i += 1024) cnt[i] = 0;
    __syncthreads();

    int e = e0 + threadIdx.x * 4;
    for (; e + 3 < e1; e += 4096) {
        const int4 d4 = *(const int4*)(dst + e);
        atomicAdd(&cnt[d4.x >> RB_SHIFT], 1);
        atomicAdd(&cnt[d4.y >> RB_SHIFT], 1);
        atomicAdd(&cnt[d4.z >> RB_SHIFT], 1);
        atomicAdd(&cnt[d4.w >> RB_SHIFT], 1);
    }
    for (; e < e1; ++e) atomicAdd(&cnt[dst[e] >> RB_SHIFT], 1);
    __syncthreads();

    for (int i = threadIdx.x; i < nbuck; i += 1024) {
        const int c = cnt[i];
        base[i] = c ? atomicAdd(&gcur[i], c) : 0;
        cnt[i] = 0;                                 // becomes local cursor
    }
    __syncthreads();

    e = e0 + threadIdx.x * 4;
    for (; e + 3 < e1; e += 4096) {
        const int4 d4 = *(const int4*)(dst + e);
        const int4 s4 = *(const int4*)(src + e);
        const float4 w4 = *(const float4*)(ew + e);
        {
            const int b = d4.x >> RB_SHIFT;
            const int p = atomicAdd(&cnt[b], 1);
            edata[(size_t)base[b] + p] = ((u64)__float_as_uint(w4.x) << 32) |
                (u32)s4.x | ((u32)(d4.x & (RB - 1)) << 20);
        }
        {
            const int b = d4.y >> RB_SHIFT;
            const int p = atomicAdd(&cnt[b], 1);
            edata[(size_t)base[b] + p] = ((u64)__float_as_uint(w4.y) << 32) |
                (u32)s4.y | ((u32)(d4.y & (RB - 1)) << 20);
        }
        {
            const int b = d4.z >> RB_SHIFT;
            const int p = atomicAdd(&cnt[b], 1);
            edata[(size_t)base[b] + p] = ((u64)__float_as_uint(w4.z) << 32) |
                (u32)s4.z | ((u32)(d4.z & (RB - 1)) << 20);
        }
        {
            const int b = d4.w >> RB_SHIFT;
            const int p = atomicAdd(&cnt[b], 1);
            edata[(size_t)base[b] + p] = ((u64)__float_as_uint(w4.w) << 32) |
                (u32)s4.w | ((u32)(d4.w & (RB - 1)) << 20);
        }
    }
    for (; e < e1; ++e) {
        const int d = dst[e];
        const int b = d >> RB_SHIFT;
        const int p = atomicAdd(&cnt[b], 1);
        edata[(size_t)base[b] + p] = ((u64)__float_as_uint(ew[e]) << 32) |
            (u32)src[e] | ((u32)(d & (RB - 1)) << 20);
    }
}

// ---------------------------------------------------------------------------
// sort: one block (1024 thr) per bucket. Counting-sort the bucket's edges by
// local dst node -> per-node-sorted edata2 + global rowptr.
// ---------------------------------------------------------------------------
__global__ __launch_bounds__(1024) void sort_kernel(
    const u64* __restrict__ edata1, const int* __restrict__ gofs,
    u64* __restrict__ edata2, int* __restrict__ rowptr, int N, int E) {
    __shared__ int cnt[RB];
    __shared__ int pref[RB];
    __shared__ int cur[RB];
    const int tid = threadIdx.x;
    const int b = blockIdx.x;
    const int s0 = gofs[b], s1 = gofs[b + 1];

    if (tid < RB) cnt[tid] = 0;
    __syncthreads();
    for (int i = s0 + tid; i < s1; i += 1024) {
        const int d = ((u32)edata1[i] >> 20) & (RB - 1);
        atomicAdd(&cnt[d], 1);
    }
    __syncthreads();
    if (tid < RB) pref[tid] = cnt[tid];
    __syncthreads();
    for (int o = 1; o < RB; o <<= 1) {
        int v = 0;
        if (tid < RB && tid >= o) v = pref[tid - o];
        __syncthreads();
        if (tid < RB) pref[tid] += v;
        __syncthreads();
    }
    if (tid < RB) {
        const int ex = pref[tid] - cnt[tid];   // exclusive prefix
        cur[tid] = ex;
        const int gn = b * RB + tid;
        if (gn < N) rowptr[gn] = s0 + ex;
    }
    if (b == 0 && tid == 0) rowptr[N] = E;
    __syncthreads();
    for (int i = s0 + tid; i < s1; i += 1024) {
        const u64 ed = edata1[i];
        const int d = ((u32)ed >> 20) & (RB - 1);
        const int p = atomicAdd(&cur[d], 1);
        edata2[(size_t)s0 + p] = ed;
    }
}

// ---------------------------------------------------------------------------
// agg64: agg[n] = b1 + sum_{e in rows[n]} w_e * h1[src_e]  (16 lanes/node,
// register accumulation, bf16 gathers)
// ---------------------------------------------------------------------------
__global__ __launch_bounds__(256) void agg64_kernel(
    const u32* __restrict__ h1b, const u64* __restrict__ edata,
    const int* __restrict__ rowptr, const float* __restrict__ bias,
    float* __restrict__ agg, int N) {
    const int tid = threadIdx.x;
    const int n = blockIdx.x * 16 + (tid >> 4);
    const int f4 = tid & 15;
    if (n >= N) return;

    float4 acc = *(const float4*)(bias + 4 * f4);
    int i = rowptr[n];
    const int end = rowptr[n + 1];

    for (; i + 1 < end; i += 2) {
        const u64 e0 = edata[i], e1 = edata[i + 1];
        const int s0 = (u32)e0 & 0xFFFFF, s1 = (u32)e1 & 0xFFFFF;
        const float w0 = __uint_as_float((u32)(e0 >> 32));
        const float w1 = __uint_as_float((u32)(e1 >> 32));
        const uint2 v0 = *(const uint2*)(h1b + (size_t)s0 * 32 + f4 * 2);
        const uint2 v1 = *(const uint2*)(h1b + (size_t)s1 * 32 + f4 * 2);
        acc.x += __uint_as_float(v0.x << 16) * w0 + __uint_as_float(v1.x << 16) * w1;
        acc.y += __uint_as_float(v0.x & 0xFFFF0000u) * w0 + __uint_as_float(v1.x & 0xFFFF0000u) * w1;
        acc.z += __uint_as_float(v0.y << 16) * w0 + __uint_as_float(v1.y << 16) * w1;
        acc.w += __uint_as_float(v0.y & 0xFFFF0000u) * w0 + __uint_as_float(v1.y & 0xFFFF0000u) * w1;
    }
    if (i < end) {
        const u64 e0 = edata[i];
        const int s0 = (u32)e0 & 0xFFFFF;
        const float w0 = __uint_as_float((u32)(e0 >> 32));
        const uint2 v0 = *(const uint2*)(h1b + (size_t)s0 * 32 + f4 * 2);
        acc.x += __uint_as_float(v0.x << 16) * w0;
        acc.y += __uint_as_float(v0.x & 0xFFFF0000u) * w0;
        acc.z += __uint_as_float(v0.y << 16) * w0;
        acc.w += __uint_as_float(v0.y & 0xFFFF0000u) * w0;
    }
    *(float4*)(agg + (size_t)n * F_H + 4 * f4) = acc;
}

// ---------------------------------------------------------------------------
// GEMM2: h2[N,16] = relu(agg1[N,64]) @ W2[64,16]  (relu fused into LDS load)
// ---------------------------------------------------------------------------
__global__ __launch_bounds__(256) void gemm2_kernel(
    const float* __restrict__ agg1, const float* __restrict__ W2,
    float* __restrict__ h2, int N) {
    __shared__ float Wlds[64 * 16];
    __shared__ float Xlds[64][65];

    const int tid = threadIdx.x;
    const int n0 = blockIdx.x * 64;

    {
        float4 v = ((const float4*)W2)[tid];
        ((float4*)Wlds)[tid] = v;
    }
    for (int i = tid; i < 64 * 16; i += 256) {
        const int row = i >> 4, c4 = i & 15;
        int n = n0 + row;
        if (n >= N) n = N - 1;
        float4 v = *(const float4*)(agg1 + (size_t)n * F_H + 4 * c4);
        Xlds[row][4 * c4 + 0] = fmaxf(v.x, 0.f);
        Xlds[row][4 * c4 + 1] = fmaxf(v.y, 0.f);
        Xlds[row][4 * c4 + 2] = fmaxf(v.z, 0.f);
        Xlds[row][4 * c4 + 3] = fmaxf(v.w, 0.f);
    }
    __syncthreads();

    const int tf4 = tid & 3;
    const int tn = tid >> 2;
    float a0 = 0.f, a1 = 0.f, a2 = 0.f, a3 = 0.f;
    #pragma unroll 8
    for (int k = 0; k < 64; ++k) {
        const float xv = Xlds[tn][k];
        float4 w4 = *(const float4*)(&Wlds[k * 16 + 4 * tf4]);
        a0 += xv * w4.x;
        a1 += xv * w4.y;
        a2 += xv * w4.z;
        a3 += xv * w4.w;
    }
    const int n = n0 + tn;
    if (n < N) {
        *(float4*)(h2 + (size_t)n * F_OUT + 4 * tf4) = make_float4(a0, a1, a2, a3);
    }
}

// ---------------------------------------------------------------------------
// agg16: out[n] = b2 + sum w_e * h2[src_e]   (4 lanes/node, register acc)
// ---------------------------------------------------------------------------
__global__ __launch_bounds__(256) void agg16_kernel(
    const float* __restrict__ h2, const u64* __restrict__ edata,
    const int* __restrict__ rowptr, const float* __restrict__ b2,
    float* __restrict__ out, int N) {
    const int tid = threadIdx.x;
    const int n = blockIdx.x * 64 + (tid >> 2);
    const int f4 = tid & 3;
    if (n >= N) return;

    float4 acc = ((const float4*)b2)[f4];
    int i = rowptr[n];
    const int end = rowptr[n + 1];

    for (; i + 1 < end; i += 2) {
        const u64 e0 = edata[i], e1 = edata[i + 1];
        const int s0 = (u32)e0 & 0xFFFFF, s1 = (u32)e1 & 0xFFFFF;
        const float w0 = __uint_as_float((u32)(e0 >> 32));
        const float w1 = __uint_as_float((u32)(e1 >> 32));
        const float4 v0 = *(const float4*)(h2 + (size_t)s0 * F_OUT + 4 * f4);
        const float4 v1 = *(const float4*)(h2 + (size_t)s1 * F_OUT + 4 * f4);
        acc.x += v0.x * w0 + v1.x * w1;
        acc.y += v0.y * w0 + v1.y * w1;
        acc.z += v0.z * w0 + v1.z * w1;
        acc.w += v0.w * w0 + v1.w * w1;
    }
    if (i < end) {
        const u64 e0 = edata[i];
        const int s0 = (u32)e0 & 0xFFFFF;
        const float w0 = __uint_as_float((u32)(e0 >> 32));
        const float4 v0 = *(const float4*)(h2 + (size_t)s0 * F_OUT + 4 * f4);
        acc.x += v0.x * w0;
        acc.y += v0.y * w0;
        acc.z += v0.z * w0;
        acc.w += v0.w * w0;
    }
    *(float4*)(out + (size_t)n * F_OUT + 4 * f4) = acc;
}

extern "C" void kernel_launch(void* const* d_in, const int* in_sizes, int n_in,
                              void* d_out, int out_size, void* d_ws, size_t ws_size,
                              hipStream_t stream) {
    const float* x   = (const float*)d_in[0];
    const int*   src = (const int*)d_in[1];
    const int*   dst = (const int*)d_in[2];
    const float* ew  = (const float*)d_in[3];
    const float* W1  = (const float*)d_in[4];
    const float* b1  = (const float*)d_in[5];
    const float* W2  = (const float*)d_in[6];
    const float* b2  = (const float*)d_in[7];
    float* out = (float*)d_out;

    const int N = in_sizes[0] / F_IN;            // 100000
    const int E = in_sizes[1];                   // 1600000
    const int nbuck = (N + RB - 1) >> RB_SHIFT;  // 782

    char* base = (char*)d_ws;
    auto align256 = [](size_t v) { return (v + 255) & ~(size_t)255; };
    size_t oR0   = 0;
    size_t oR1   = align256(oR0 + (size_t)N * 32 * 4);   // h1b bf16 / h2
    size_t oR2   = align256(oR1 + (size_t)N * F_H * 4);  // edata1 / agg1
    size_t oROW  = align256(oR2 + (size_t)E * 8);        // edata2
    size_t oHIST = align256(oROW + (size_t)(N + 1) * 4);
    size_t oOFS  = align256(oHIST + (size_t)nbuck * 4);
    size_t oCUR  = align256(oOFS + (size_t)(nbuck + 1) * 4);
    (void)ws_size;

    u32*   h1b    = (u32*)(base + oR0);
    float* h2     = (float*)(base + oR0);
    u64*   edata1 = (u64*)(base + oR1);
    float* agg1   = (float*)(base + oR1);
    u64*   edata2 = (u64*)(base + oR2);
    int*   rowptr = (int*)(base + oROW);
    int*   hist   = (int*)(base + oHIST);
    int*   gofs   = (int*)(base + oOFS);
    int*   gcur   = (int*)(base + oCUR);

    // ---- graph preprocessing: bucket sort -> per-node sort
    hipMemsetAsync(hist, 0, (size_t)nbuck * 4, stream);
    hist_kernel<<<256, 1024, 0, stream>>>(dst, hist, E, nbuck);
    scan_kernel<<<1, 1024, 0, stream>>>(hist, gofs, gcur, nbuck, E);
    fill_kernel<<<256, 1024, 0, stream>>>(src, dst, ew, gcur, edata1, E, nbuck);
    sort_kernel<<<nbuck, 1024, 0, stream>>>(edata1, gofs, edata2, rowptr, N, E);

    // ---- layer 1
    gemm1_kernel<<<(N + 63) / 64, 256, 0, stream>>>(x, W1, h1b, N);
    agg64_kernel<<<(N + 15) / 16, 256, 0, stream>>>(h1b, edata2, rowptr, b1, agg1, N);

    // ---- layer 2
    gemm2_kernel<<<(N + 63) / 64, 256, 0, stream>>>(agg1, W2, h2, N);
    agg16_kernel<<<(N + 63) / 64, 256, 0, stream>>>(h2, edata2, rowptr, b2, out, N);
}

// Round 6
// 167.162 us; speedup vs baseline: 5.6448x; 1.0117x over previous
//
#include <hip/hip_runtime.h>

#define F_IN 128
#define F_H 64
#define F_OUT 16
#define RB 128           // nodes per bucket
#define RB_SHIFT 7       // bucket = dst >> 7
#define DBINS 64         // degree bins for node permutation

typedef unsigned long long u64;
typedef unsigned int u32;

__device__ __forceinline__ u32 pack2bf16(float a, float b) {
    u32 ua = (__float_as_uint(a) + 0x8000u) >> 16;
    u32 ub = (__float_as_uint(b) + 0x8000u) & 0xFFFF0000u;
    return ua | ub;
}

// ---------------------------------------------------------------------------
// GEMM1: h1[N,64](bf16 packed in u32 pairs) = x[N,128] @ W1[128,64]
// ---------------------------------------------------------------------------
__global__ __launch_bounds__(256) void gemm1_kernel(
    const float* __restrict__ x, const float* __restrict__ W,
    u32* __restrict__ h1b, int N) {
    __shared__ float Wlds[64 * 64];
    __shared__ float Xlds[64][69];

    const int tid = threadIdx.x;
    const int n0 = blockIdx.x * 64;
    const int tf = tid & 15;
    const int tn = tid >> 4;

    float acc[4][4] = {{0.f, 0.f, 0.f, 0.f}, {0.f, 0.f, 0.f, 0.f},
                       {0.f, 0.f, 0.f, 0.f}, {0.f, 0.f, 0.f, 0.f}};

    for (int p = 0; p < 2; ++p) {
        for (int i = tid; i < 1024; i += 256) {
            const int kk = i >> 4, c4 = i & 15;
            float4 v = *(const float4*)(W + (size_t)(64 * p + kk) * 64 + 4 * c4);
            *(float4*)(&Wlds[kk * 64 + 4 * c4]) = v;
        }
        for (int i = tid; i < 1024; i += 256) {
            const int row = i >> 4, c4 = i & 15;
            int n = n0 + row;
            if (n >= N) n = N - 1;
            float4 v = *(const float4*)(x + (size_t)n * F_IN + 64 * p + 4 * c4);
            Xlds[row][4 * c4 + 0] = v.x;
            Xlds[row][4 * c4 + 1] = v.y;
            Xlds[row][4 * c4 + 2] = v.z;
            Xlds[row][4 * c4 + 3] = v.w;
        }
        __syncthreads();

        #pragma unroll 4
        for (int kk = 0; kk < 64; ++kk) {
            float4 w4 = *(const float4*)(&Wlds[kk * 64 + 4 * tf]);
            float xv[4];
            #pragma unroll
            for (int i2 = 0; i2 < 4; ++i2) xv[i2] = Xlds[4 * tn + i2][kk];
            #pragma unroll
            for (int i2 = 0; i2 < 4; ++i2) {
                acc[i2][0] += xv[i2] * w4.x;
                acc[i2][1] += xv[i2] * w4.y;
                acc[i2][2] += xv[i2] * w4.z;
                acc[i2][3] += xv[i2] * w4.w;
            }
        }
        __syncthreads();
    }

    #pragma unroll
    for (int i2 = 0; i2 < 4; ++i2) {
        const int n = n0 + 4 * tn + i2;
        if (n < N) {
            uint2 o = make_uint2(pack2bf16(acc[i2][0], acc[i2][1]),
                                 pack2bf16(acc[i2][2], acc[i2][3]));
            *(uint2*)(h1b + (size_t)n * 32 + tf * 2) = o;   // feats 4*tf..4*tf+3
        }
    }
}

// ---------------------------------------------------------------------------
// bucket histogram (LDS-staged, int4 reads, 1024 threads)
// ---------------------------------------------------------------------------
__global__ __launch_bounds__(1024) void hist_kernel(
    const int* __restrict__ dst, int* __restrict__ hist, int E, int nbuck) {
    __shared__ int h[800];
    for (int i = threadIdx.x; i < nbuck; i += 1024) h[i] = 0;
    __syncthreads();
    const int nstep = gridDim.x * 1024;
    int e = (blockIdx.x * 1024 + threadIdx.x) * 4;
    for (; e + 3 < E; e += nstep * 4) {
        const int4 d4 = *(const int4*)(dst + e);
        atomicAdd(&h[d4.x >> RB_SHIFT], 1);
        atomicAdd(&h[d4.y >> RB_SHIFT], 1);
        atomicAdd(&h[d4.z >> RB_SHIFT], 1);
        atomicAdd(&h[d4.w >> RB_SHIFT], 1);
    }
    for (; e < E; ++e) atomicAdd(&h[dst[e] >> RB_SHIFT], 1);
    __syncthreads();
    for (int i = threadIdx.x; i < nbuck; i += 1024)
        if (h[i]) atomicAdd(&hist[i], h[i]);
}

// ---------------------------------------------------------------------------
// exclusive scan of bucket counts (single block; nbuck <= 1024)
// ---------------------------------------------------------------------------
__global__ __launch_bounds__(1024) void scan_kernel(
    const int* __restrict__ hist, int* __restrict__ gofs, int* __restrict__ gcur,
    int nbuck, int E) {
    __shared__ int s[1024];
    const int t = threadIdx.x;
    const int v = (t < nbuck) ? hist[t] : 0;
    s[t] = v;
    __syncthreads();
    for (int o = 1; o < 1024; o <<= 1) {
        int a = (t >= o) ? s[t - o] : 0;
        __syncthreads();
        s[t] += a;
        __syncthreads();
    }
    if (t < nbuck) {
        const int ex = s[t] - v;
        gofs[t] = ex;
        gcur[t] = ex;
    }
    if (t == 0) gofs[nbuck] = E;
}

// ---------------------------------------------------------------------------
// fill: block-local counting sort into bucket-grouped edata1
// entry: [63:32]=weight f32 bits, [26:20]=dst&127, [19:0]=src
// ---------------------------------------------------------------------------
__global__ __launch_bounds__(1024) void fill_kernel(
    const int* __restrict__ src, const int* __restrict__ dst,
    const float* __restrict__ ew, int* __restrict__ gcur,
    u64* __restrict__ edata, int E, int nbuck) {
    __shared__ int cnt[800];
    __shared__ int base[800];
    int chunk = (E + gridDim.x - 1) / gridDim.x;
    chunk = (chunk + 3) & ~3;
    const int e0 = blockIdx.x * chunk;
    const int e1 = min(e0 + chunk, E);

    for (int i = threadIdx.x; i < nbuck; i += 1024) cnt[i] = 0;
    __syncthreads();

    int e = e0 + threadIdx.x * 4;
    for (; e + 3 < e1; e += 4096) {
        const int4 d4 = *(const int4*)(dst + e);
        atomicAdd(&cnt[d4.x >> RB_SHIFT], 1);
        atomicAdd(&cnt[d4.y >> RB_SHIFT], 1);
        atomicAdd(&cnt[d4.z >> RB_SHIFT], 1);
        atomicAdd(&cnt[d4.w >> RB_SHIFT], 1);
    }
    for (; e < e1; ++e) atomicAdd(&cnt[dst[e] >> RB_SHIFT], 1);
    __syncthreads();

    for (int i = threadIdx.x; i < nbuck; i += 1024) {
        const int c = cnt[i];
        base[i] = c ? atomicAdd(&gcur[i], c) : 0;
        cnt[i] = 0;
    }
    __syncthreads();

    e = e0 + threadIdx.x * 4;
    for (; e + 3 < e1; e += 4096) {
        const int4 d4 = *(const int4*)(dst + e);
        const int4 s4 = *(const int4*)(src + e);
        const float4 w4 = *(const float4*)(ew + e);
        {
            const int b = d4.x >> RB_SHIFT;
            const int p = atomicAdd(&cnt[b], 1);
            edata[(size_t)base[b] + p] = ((u64)__float_as_uint(w4.x) << 32) |
                (u32)s4.x | ((u32)(d4.x & (RB - 1)) << 20);
        }
        {
            const int b = d4.y >> RB_SHIFT;
            const int p = atomicAdd(&cnt[b], 1);
            edata[(size_t)base[b] + p] = ((u64)__float_as_uint(w4.y) << 32) |
                (u32)s4.y | ((u32)(d4.y & (RB - 1)) << 20);
        }
        {
            const int b = d4.z >> RB_SHIFT;
            const int p = atomicAdd(&cnt[b], 1);
            edata[(size_t)base[b] + p] = ((u64)__float_as_uint(w4.z) << 32) |
                (u32)s4.z | ((u32)(d4.z & (RB - 1)) << 20);
        }
        {
            const int b = d4.w >> RB_SHIFT;
            const int p = atomicAdd(&cnt[b], 1);
            edata[(size_t)base[b] + p] = ((u64)__float_as_uint(w4.w) << 32) |
                (u32)s4.w | ((u32)(d4.w & (RB - 1)) << 20);
        }
    }
    for (; e < e1; ++e) {
        const int d = dst[e];
        const int b = d >> RB_SHIFT;
        const int p = atomicAdd(&cnt[b], 1);
        edata[(size_t)base[b] + p] = ((u64)__float_as_uint(ew[e]) << 32) |
            (u32)src[e] | ((u32)(d & (RB - 1)) << 20);
    }
}

// ---------------------------------------------------------------------------
// sort: one block (1024 thr) per bucket -> per-node-sorted edata2 + rowptr
// ---------------------------------------------------------------------------
__global__ __launch_bounds__(1024) void sort_kernel(
    const u64* __restrict__ edata1, const int* __restrict__ gofs,
    u64* __restrict__ edata2, int* __restrict__ rowptr, int N, int E) {
    __shared__ int cnt[RB];
    __shared__ int pref[RB];
    __shared__ int cur[RB];
    const int tid = threadIdx.x;
    const int b = blockIdx.x;
    const int s0 = gofs[b], s1 = gofs[b + 1];

    if (tid < RB) cnt[tid] = 0;
    __syncthreads();
    for (int i = s0 + tid; i < s1; i += 1024) {
        const int d = ((u32)edata1[i] >> 20) & (RB - 1);
        atomicAdd(&cnt[d], 1);
    }
    __syncthreads();
    if (tid < RB) pref[tid] = cnt[tid];
    __syncthreads();
    for (int o = 1; o < RB; o <<= 1) {
        int v = 0;
        if (tid < RB && tid >= o) v = pref[tid - o];
        __syncthreads();
        if (tid < RB) pref[tid] += v;
        __syncthreads();
    }
    if (tid < RB) {
        const int ex = pref[tid] - cnt[tid];
        cur[tid] = ex;
        const int gn = b * RB + tid;
        if (gn < N) rowptr[gn] = s0 + ex;
    }
    if (b == 0 && tid == 0) rowptr[N] = E;
    __syncthreads();
    for (int i = s0 + tid; i < s1; i += 1024) {
        const u64 ed = edata1[i];
        const int d = ((u32)ed >> 20) & (RB - 1);
        const int p = atomicAdd(&cur[d], 1);
        edata2[(size_t)s0 + p] = ed;
    }
}

// ---------------------------------------------------------------------------
// degree-bin histogram (64 bins, deg capped at 63)
// ---------------------------------------------------------------------------
__global__ __launch_bounds__(256) void dhist_kernel(
    const int* __restrict__ rowptr, int* __restrict__ dhist, int N) {
    __shared__ int h[DBINS];
    if (threadIdx.x < DBINS) h[threadIdx.x] = 0;
    __syncthreads();
    for (int n = blockIdx.x * 256 + threadIdx.x; n < N; n += gridDim.x * 256) {
        const int deg = rowptr[n + 1] - rowptr[n];
        atomicAdd(&h[min(deg, DBINS - 1)], 1);
    }
    __syncthreads();
    if (threadIdx.x < DBINS && h[threadIdx.x])
        atomicAdd(&dhist[threadIdx.x], h[threadIdx.x]);
}

__global__ __launch_bounds__(64) void dscan_kernel(
    const int* __restrict__ dhist, int* __restrict__ dcur) {
    __shared__ int s[DBINS];
    const int t = threadIdx.x;
    const int v = dhist[t];
    s[t] = v;
    __syncthreads();
    for (int o = 1; o < DBINS; o <<= 1) {
        int a = (t >= o) ? s[t - o] : 0;
        __syncthreads();
        s[t] += a;
        __syncthreads();
    }
    dcur[t] = s[t] - v;   // exclusive
}

// ---------------------------------------------------------------------------
// dperm: scatter nodes into degree-sorted permutation (block-local staging)
// ---------------------------------------------------------------------------
__global__ __launch_bounds__(256) void dperm_kernel(
    const int* __restrict__ rowptr, int* __restrict__ dcur,
    int* __restrict__ perm, int N) {
    __shared__ int cnt[DBINS];
    __shared__ int base[DBINS];
    const int chunk = (N + gridDim.x - 1) / gridDim.x;
    const int n0 = blockIdx.x * chunk;
    const int n1 = min(n0 + chunk, N);

    if (threadIdx.x < DBINS) cnt[threadIdx.x] = 0;
    __syncthreads();
    for (int n = n0 + threadIdx.x; n < n1; n += 256) {
        const int deg = rowptr[n + 1] - rowptr[n];
        atomicAdd(&cnt[min(deg, DBINS - 1)], 1);
    }
    __syncthreads();
    if (threadIdx.x < DBINS) {
        const int c = cnt[threadIdx.x];
        base[threadIdx.x] = c ? atomicAdd(&dcur[threadIdx.x], c) : 0;
        cnt[threadIdx.x] = 0;
    }
    __syncthreads();
    for (int n = n0 + threadIdx.x; n < n1; n += 256) {
        const int b = min(rowptr[n + 1] - rowptr[n], DBINS - 1);
        const int p = atomicAdd(&cnt[b], 1);
        perm[base[b] + p] = n;
    }
}

// ---------------------------------------------------------------------------
// agg64fused: per node n=perm[idx] (16 lanes/node):
//   acc = b1 + sum w_e * h1[src_e]          (register acc, bf16 gathers)
//   h2b[n] = bf16( relu(acc) @ W2 )         (shfl-broadcast mini-GEMM)
// ---------------------------------------------------------------------------
__global__ __launch_bounds__(256) void agg64fused_kernel(
    const u32* __restrict__ h1b, const u64* __restrict__ edata,
    const int* __restrict__ rowptr, const int* __restrict__ perm,
    const float* __restrict__ b1, const float* __restrict__ W2,
    u32* __restrict__ h2b, int N) {
    __shared__ float w2t[16][68];        // W2 transposed [col][k]

    const int tid = threadIdx.x;
    for (int i = tid; i < 1024; i += 256)
        w2t[i & 15][i >> 4] = W2[i];     // W2[k][c] -> w2t[c][k]
    __syncthreads();

    const int idx = blockIdx.x * 16 + (tid >> 4);
    if (idx >= N) return;
    const int n = perm[idx];
    const int f4 = tid & 15;

    float4 acc = *(const float4*)(b1 + 4 * f4);
    int i = rowptr[n];
    const int end = rowptr[n + 1];

    for (; i + 3 < end; i += 4) {
        const u64 e0 = edata[i], e1 = edata[i + 1], e2 = edata[i + 2], e3 = edata[i + 3];
        const int s0 = (u32)e0 & 0xFFFFF, s1 = (u32)e1 & 0xFFFFF;
        const int s2 = (u32)e2 & 0xFFFFF, s3 = (u32)e3 & 0xFFFFF;
        const float w0 = __uint_as_float((u32)(e0 >> 32));
        const float w1 = __uint_as_float((u32)(e1 >> 32));
        const float w2 = __uint_as_float((u32)(e2 >> 32));
        const float w3 = __uint_as_float((u32)(e3 >> 32));
        const uint2 v0 = *(const uint2*)(h1b + (size_t)s0 * 32 + f4 * 2);
        const uint2 v1 = *(const uint2*)(h1b + (size_t)s1 * 32 + f4 * 2);
        const uint2 v2 = *(const uint2*)(h1b + (size_t)s2 * 32 + f4 * 2);
        const uint2 v3 = *(const uint2*)(h1b + (size_t)s3 * 32 + f4 * 2);
        acc.x += __uint_as_float(v0.x << 16) * w0 + __uint_as_float(v1.x << 16) * w1
               + __uint_as_float(v2.x << 16) * w2 + __uint_as_float(v3.x << 16) * w3;
        acc.y += __uint_as_float(v0.x & 0xFFFF0000u) * w0 + __uint_as_float(v1.x & 0xFFFF0000u) * w1
               + __uint_as_float(v2.x & 0xFFFF0000u) * w2 + __uint_as_float(v3.x & 0xFFFF0000u) * w3;
        acc.z += __uint_as_float(v0.y << 16) * w0 + __uint_as_float(v1.y << 16) * w1
               + __uint_as_float(v2.y << 16) * w2 + __uint_as_float(v3.y << 16) * w3;
        acc.w += __uint_as_float(v0.y & 0xFFFF0000u) * w0 + __uint_as_float(v1.y & 0xFFFF0000u) * w1
               + __uint_as_float(v2.y & 0xFFFF0000u) * w2 + __uint_as_float(v3.y & 0xFFFF0000u) * w3;
    }
    for (; i < end; ++i) {
        const u64 e0 = edata[i];
        const int s0 = (u32)e0 & 0xFFFFF;
        const float w0 = __uint_as_float((u32)(e0 >> 32));
        const uint2 v0 = *(const uint2*)(h1b + (size_t)s0 * 32 + f4 * 2);
        acc.x += __uint_as_float(v0.x << 16) * w0;
        acc.y += __uint_as_float(v0.x & 0xFFFF0000u) * w0;
        acc.z += __uint_as_float(v0.y << 16) * w0;
        acc.w += __uint_as_float(v0.y & 0xFFFF0000u) * w0;
    }

    // mini-GEMM: o[c] = sum_k relu(acc_k) * W2[k][c], c = f4
    float racc[4] = {fmaxf(acc.x, 0.f), fmaxf(acc.y, 0.f),
                     fmaxf(acc.z, 0.f), fmaxf(acc.w, 0.f)};
    const int gb = (tid & 63) & 48;      // wave-local 16-lane group base
    float o = 0.f;
    #pragma unroll
    for (int k4 = 0; k4 < 16; ++k4) {    // k = 4*k4 + m, owner lane = gb+k4
        const float4 w4 = *(const float4*)(&w2t[f4][k4 * 4]);
        const float r0 = __shfl(racc[0], gb + k4, 64);
        const float r1 = __shfl(racc[1], gb + k4, 64);
        const float r2 = __shfl(racc[2], gb + k4, 64);
        const float r3 = __shfl(racc[3], gb + k4, 64);
        o += r0 * w4.x + r1 * w4.y + r2 * w4.z + r3 * w4.w;
    }
    // pack cols 2j,2j+1 on even lanes, write bf16 row (32B)
    const float o_hi = __shfl_down(o, 1, 64);
    if ((tid & 1) == 0) {
        h2b[(size_t)n * 8 + (f4 >> 1)] = pack2bf16(o, o_hi);
    }
}

// ---------------------------------------------------------------------------
// agg16: out[n] = b2 + sum w_e * h2b[src_e]  (2 lanes/node, bf16 gathers)
// ---------------------------------------------------------------------------
__global__ __launch_bounds__(256) void agg16_kernel(
    const u32* __restrict__ h2b, const u64* __restrict__ edata,
    const int* __restrict__ rowptr, const int* __restrict__ perm,
    const float* __restrict__ b2, float* __restrict__ out, int N) {
    const int tid = threadIdx.x;
    const int idx = blockIdx.x * 128 + (tid >> 1);
    if (idx >= N) return;
    const int n = perm[idx];
    const int lane = tid & 1;            // feats lane*8 .. lane*8+7

    float acc[8];
    {
        const float4 ba = *(const float4*)(b2 + lane * 8);
        const float4 bb = *(const float4*)(b2 + lane * 8 + 4);
        acc[0] = ba.x; acc[1] = ba.y; acc[2] = ba.z; acc[3] = ba.w;
        acc[4] = bb.x; acc[5] = bb.y; acc[6] = bb.z; acc[7] = bb.w;
    }
    int i = rowptr[n];
    const int end = rowptr[n + 1];

    for (; i + 1 < end; i += 2) {
        const u64 e0 = edata[i], e1 = edata[i + 1];
        const int s0 = (u32)e0 & 0xFFFFF, s1 = (u32)e1 & 0xFFFFF;
        const float w0 = __uint_as_float((u32)(e0 >> 32));
        const float w1 = __uint_as_float((u32)(e1 >> 32));
        const uint4 v0 = *(const uint4*)(h2b + (size_t)s0 * 8 + lane * 4);
        const uint4 v1 = *(const uint4*)(h2b + (size_t)s1 * 8 + lane * 4);
        acc[0] += __uint_as_float(v0.x << 16) * w0 + __uint_as_float(v1.x << 16) * w1;
        acc[1] += __uint_as_float(v0.x & 0xFFFF0000u) * w0 + __uint_as_float(v1.x & 0xFFFF0000u) * w1;
        acc[2] += __uint_as_float(v0.y << 16) * w0 + __uint_as_float(v1.y << 16) * w1;
        acc[3] += __uint_as_float(v0.y & 0xFFFF0000u) * w0 + __uint_as_float(v1.y & 0xFFFF0000u) * w1;
        acc[4] += __uint_as_float(v0.z << 16) * w0 + __uint_as_float(v1.z << 16) * w1;
        acc[5] += __uint_as_float(v0.z & 0xFFFF0000u) * w0 + __uint_as_float(v1.z & 0xFFFF0000u) * w1;
        acc[6] += __uint_as_float(v0.w << 16) * w0 + __uint_as_float(v1.w << 16) * w1;
        acc[7] += __uint_as_float(v0.w & 0xFFFF0000u) * w0 + __uint_as_float(v1.w & 0xFFFF0000u) * w1;
    }
    if (i < end) {
        const u64 e0 = edata[i];
        const int s0 = (u32)e0 & 0xFFFFF;
        const float w0 = __uint_as_float((u32)(e0 >> 32));
        const uint4 v0 = *(const uint4*)(h2b + (size_t)s0 * 8 + lane * 4);
        acc[0] += __uint_as_float(v0.x << 16) * w0;
        acc[1] += __uint_as_float(v0.x & 0xFFFF0000u) * w0;
        acc[2] += __uint_as_float(v0.y << 16) * w0;
        acc[3] += __uint_as_float(v0.y & 0xFFFF0000u) * w0;
        acc[4] += __uint_as_float(v0.z << 16) * w0;
        acc[5] += __uint_as_float(v0.z & 0xFFFF0000u) * w0;
        acc[6] += __uint_as_float(v0.w << 16) * w0;
        acc[7] += __uint_as_float(v0.w & 0xFFFF0000u) * w0;
    }
    float* p = out + (size_t)n * F_OUT + lane * 8;
    *(float4*)(p + 0) = make_float4(acc[0], acc[1], acc[2], acc[3]);
    *(float4*)(p + 4) = make_float4(acc[4], acc[5], acc[6], acc[7]);
}

extern "C" void kernel_launch(void* const* d_in, const int* in_sizes, int n_in,
                              void* d_out, int out_size, void* d_ws, size_t ws_size,
                              hipStream_t stream) {
    const float* x   = (const float*)d_in[0];
    const int*   src = (const int*)d_in[1];
    const int*   dst = (const int*)d_in[2];
    const float* ew  = (const float*)d_in[3];
    const float* W1  = (const float*)d_in[4];
    const float* b1  = (const float*)d_in[5];
    const float* W2  = (const float*)d_in[6];
    const float* b2  = (const float*)d_in[7];
    float* out = (float*)d_out;

    const int N = in_sizes[0] / F_IN;            // 100000
    const int E = in_sizes[1];                   // 1600000
    const int nbuck = (N + RB - 1) >> RB_SHIFT;  // 782

    char* base = (char*)d_ws;
    auto align256 = [](size_t v) { return (v + 255) & ~(size_t)255; };
    size_t oH1   = 0;
    size_t oED1  = align256(oH1  + (size_t)N * 32 * 4);      // h1b bf16 12.8MB
    size_t oED2  = align256(oED1 + (size_t)E * 8);           // edata1 12.8MB
    size_t oH2B  = align256(oED2 + (size_t)E * 8);           // edata2 12.8MB
    size_t oROW  = align256(oH2B + (size_t)N * 8 * 4);       // h2b bf16 3.2MB
    size_t oPERM = align256(oROW + (size_t)(N + 1) * 4);
    size_t oHIST = align256(oPERM + (size_t)N * 4);
    size_t oOFS  = align256(oHIST + (size_t)nbuck * 4);
    size_t oCUR  = align256(oOFS + (size_t)(nbuck + 1) * 4);
    size_t oDH   = align256(oCUR + (size_t)nbuck * 4);
    size_t oDC   = align256(oDH + DBINS * 4);
    (void)ws_size;

    u32*   h1b    = (u32*)(base + oH1);
    u64*   edata1 = (u64*)(base + oED1);
    u64*   edata2 = (u64*)(base + oED2);
    u32*   h2b    = (u32*)(base + oH2B);
    int*   rowptr = (int*)(base + oROW);
    int*   perm   = (int*)(base + oPERM);
    int*   hist   = (int*)(base + oHIST);
    int*   gofs   = (int*)(base + oOFS);
    int*   gcur   = (int*)(base + oCUR);
    int*   dhist  = (int*)(base + oDH);
    int*   dcur   = (int*)(base + oDC);

    // ---- graph preprocessing: bucket sort -> per-node sort -> degree perm
    hipMemsetAsync(hist, 0, (size_t)nbuck * 4, stream);
    hipMemsetAsync(dhist, 0, DBINS * 4, stream);
    hist_kernel<<<256, 1024, 0, stream>>>(dst, hist, E, nbuck);
    scan_kernel<<<1, 1024, 0, stream>>>(hist, gofs, gcur, nbuck, E);
    fill_kernel<<<256, 1024, 0, stream>>>(src, dst, ew, gcur, edata1, E, nbuck);
    sort_kernel<<<nbuck, 1024, 0, stream>>>(edata1, gofs, edata2, rowptr, N, E);
    dhist_kernel<<<128, 256, 0, stream>>>(rowptr, dhist, N);
    dscan_kernel<<<1, 64, 0, stream>>>(dhist, dcur);
    dperm_kernel<<<128, 256, 0, stream>>>(rowptr, dcur, perm, N);

    // ---- layer 1 transform
    gemm1_kernel<<<(N + 63) / 64, 256, 0, stream>>>(x, W1, h1b, N);
    // ---- layer-1 aggregate + relu + W2 (fused), h2 in bf16
    agg64fused_kernel<<<(N + 15) / 16, 256, 0, stream>>>(
        h1b, edata2, rowptr, perm, b1, W2, h2b, N);
    // ---- layer-2 aggregate + bias
    agg16_kernel<<<(N + 127) / 128, 256, 0, stream>>>(
        h2b, edata2, rowptr, perm, b2, out, N);
}

// Round 7
// 141.074 us; speedup vs baseline: 6.6887x; 1.1849x over previous
//
#include <hip/hip_runtime.h>

#define F_IN 128
#define F_H 64
#define F_OUT 16
#define RB 128           // nodes per bucket
#define RB_SHIFT 7       // bucket = dst >> 7
#define DBINS 64         // degree bins for bucket-local degree ranking
#define CAP 3072         // fixed bucket capacity (mean 2046, sigma ~45 -> +22 sigma)

typedef unsigned long long u64;
typedef unsigned int u32;

__device__ __forceinline__ u32 pack2bf16(float a, float b) {
    u32 ua = (__float_as_uint(a) + 0x8000u) >> 16;
    u32 ub = (__float_as_uint(b) + 0x8000u) & 0xFFFF0000u;
    return ua | ub;
}

// ---------------------------------------------------------------------------
// GEMM1: h1[N,64](bf16 packed in u32 pairs) = x[N,128] @ W1[128,64]
// ---------------------------------------------------------------------------
__global__ __launch_bounds__(256) void gemm1_kernel(
    const float* __restrict__ x, const float* __restrict__ W,
    u32* __restrict__ h1b, int N) {
    __shared__ float Wlds[64 * 64];
    __shared__ float Xlds[64][69];

    const int tid = threadIdx.x;
    const int n0 = blockIdx.x * 64;
    const int tf = tid & 15;
    const int tn = tid >> 4;

    float acc[4][4] = {{0.f, 0.f, 0.f, 0.f}, {0.f, 0.f, 0.f, 0.f},
                       {0.f, 0.f, 0.f, 0.f}, {0.f, 0.f, 0.f, 0.f}};

    for (int p = 0; p < 2; ++p) {
        for (int i = tid; i < 1024; i += 256) {
            const int kk = i >> 4, c4 = i & 15;
            float4 v = *(const float4*)(W + (size_t)(64 * p + kk) * 64 + 4 * c4);
            *(float4*)(&Wlds[kk * 64 + 4 * c4]) = v;
        }
        for (int i = tid; i < 1024; i += 256) {
            const int row = i >> 4, c4 = i & 15;
            int n = n0 + row;
            if (n >= N) n = N - 1;
            float4 v = *(const float4*)(x + (size_t)n * F_IN + 64 * p + 4 * c4);
            Xlds[row][4 * c4 + 0] = v.x;
            Xlds[row][4 * c4 + 1] = v.y;
            Xlds[row][4 * c4 + 2] = v.z;
            Xlds[row][4 * c4 + 3] = v.w;
        }
        __syncthreads();

        #pragma unroll 4
        for (int kk = 0; kk < 64; ++kk) {
            float4 w4 = *(const float4*)(&Wlds[kk * 64 + 4 * tf]);
            float xv[4];
            #pragma unroll
            for (int i2 = 0; i2 < 4; ++i2) xv[i2] = Xlds[4 * tn + i2][kk];
            #pragma unroll
            for (int i2 = 0; i2 < 4; ++i2) {
                acc[i2][0] += xv[i2] * w4.x;
                acc[i2][1] += xv[i2] * w4.y;
                acc[i2][2] += xv[i2] * w4.z;
                acc[i2][3] += xv[i2] * w4.w;
            }
        }
        __syncthreads();
    }

    #pragma unroll
    for (int i2 = 0; i2 < 4; ++i2) {
        const int n = n0 + 4 * tn + i2;
        if (n < N) {
            uint2 o = make_uint2(pack2bf16(acc[i2][0], acc[i2][1]),
                                 pack2bf16(acc[i2][2], acc[i2][3]));
            *(uint2*)(h1b + (size_t)n * 32 + tf * 2) = o;
        }
    }
}

// ---------------------------------------------------------------------------
// fill: block-local counting sort into CAP-strided bucket-grouped edata1
// entry: [63:32]=weight f32 bits, [26:20]=dst&127, [19:0]=src
// gcur[b] (zeroed before) ends as the bucket's edge count.
// ---------------------------------------------------------------------------
__global__ __launch_bounds__(1024) void fill_kernel(
    const int* __restrict__ src, const int* __restrict__ dst,
    const float* __restrict__ ew, int* __restrict__ gcur,
    u64* __restrict__ edata, int E, int nbuck) {
    __shared__ int cnt[800];
    __shared__ int base[800];
    int chunk = (E + gridDim.x - 1) / gridDim.x;
    chunk = (chunk + 3) & ~3;
    const int e0 = blockIdx.x * chunk;
    const int e1 = min(e0 + chunk, E);

    for (int i = threadIdx.x; i < nbuck; i += 1024) cnt[i] = 0;
    __syncthreads();

    int e = e0 + threadIdx.x * 4;
    for (; e + 3 < e1; e += 4096) {
        const int4 d4 = *(const int4*)(dst + e);
        atomicAdd(&cnt[d4.x >> RB_SHIFT], 1);
        atomicAdd(&cnt[d4.y >> RB_SHIFT], 1);
        atomicAdd(&cnt[d4.z >> RB_SHIFT], 1);
        atomicAdd(&cnt[d4.w >> RB_SHIFT], 1);
    }
    for (; e < e1; ++e) atomicAdd(&cnt[dst[e] >> RB_SHIFT], 1);
    __syncthreads();

    for (int i = threadIdx.x; i < nbuck; i += 1024) {
        const int c = cnt[i];
        base[i] = i * CAP + (c ? atomicAdd(&gcur[i], c) : 0);
        cnt[i] = 0;
    }
    __syncthreads();

    e = e0 + threadIdx.x * 4;
    for (; e + 3 < e1; e += 4096) {
        const int4 d4 = *(const int4*)(dst + e);
        const int4 s4 = *(const int4*)(src + e);
        const float4 w4 = *(const float4*)(ew + e);
        {
            const int b = d4.x >> RB_SHIFT;
            const int p = atomicAdd(&cnt[b], 1);
            edata[(size_t)base[b] + p] = ((u64)__float_as_uint(w4.x) << 32) |
                (u32)s4.x | ((u32)(d4.x & (RB - 1)) << 20);
        }
        {
            const int b = d4.y >> RB_SHIFT;
            const int p = atomicAdd(&cnt[b], 1);
            edata[(size_t)base[b] + p] = ((u64)__float_as_uint(w4.y) << 32) |
                (u32)s4.y | ((u32)(d4.y & (RB - 1)) << 20);
        }
        {
            const int b = d4.z >> RB_SHIFT;
            const int p = atomicAdd(&cnt[b], 1);
            edata[(size_t)base[b] + p] = ((u64)__float_as_uint(w4.z) << 32) |
                (u32)s4.z | ((u32)(d4.z & (RB - 1)) << 20);
        }
        {
            const int b = d4.w >> RB_SHIFT;
            const int p = atomicAdd(&cnt[b], 1);
            edata[(size_t)base[b] + p] = ((u64)__float_as_uint(w4.w) << 32) |
                (u32)s4.w | ((u32)(d4.w & (RB - 1)) << 20);
        }
    }
    for (; e < e1; ++e) {
        const int d = dst[e];
        const int b = d >> RB_SHIFT;
        const int p = atomicAdd(&cnt[b], 1);
        edata[(size_t)base[b] + p] = ((u64)__float_as_uint(ew[e]) << 32) |
            (u32)src[e] | ((u32)(d & (RB - 1)) << 20);
    }
}

// ---------------------------------------------------------------------------
// sort: one block (1024 thr) per bucket.
//  - counting-sort bucket edges by local dst node -> edata2 (CAP-strided)
//  - rowbeg/rowend per node
//  - bucket-local degree-ranked perm (equal-degree nodes adjacent; locality!)
// ---------------------------------------------------------------------------
__global__ __launch_bounds__(1024) void sort_kernel(
    const u64* __restrict__ edata1, const int* __restrict__ gcnt,
    u64* __restrict__ edata2, int* __restrict__ rowbeg, int* __restrict__ rowend,
    int* __restrict__ perm, int N) {
    __shared__ int cnt[RB];
    __shared__ int pref[RB];
    __shared__ int cur[RB];
    __shared__ int dbin[DBINS];
    __shared__ int dcur[DBINS];
    const int tid = threadIdx.x;
    const int b = blockIdx.x;
    const int s0 = b * CAP;
    const int s1 = s0 + gcnt[b];

    if (tid < RB) cnt[tid] = 0;
    if (tid < DBINS) dbin[tid] = 0;
    __syncthreads();
    for (int i = s0 + tid; i < s1; i += 1024) {
        const int d = ((u32)edata1[i] >> 20) & (RB - 1);
        atomicAdd(&cnt[d], 1);
    }
    __syncthreads();
    if (tid < RB) pref[tid] = cnt[tid];
    __syncthreads();
    for (int o = 1; o < RB; o <<= 1) {
        int v = 0;
        if (tid < RB && tid >= o) v = pref[tid - o];
        __syncthreads();
        if (tid < RB) pref[tid] += v;
        __syncthreads();
    }
    const int gn = b * RB + tid;
    if (tid < RB) {
        const int ex = pref[tid] - cnt[tid];
        cur[tid] = ex;
        if (gn < N) {
            rowbeg[gn] = s0 + ex;
            rowend[gn] = s0 + ex + cnt[tid];
            atomicAdd(&dbin[min(cnt[tid], DBINS - 1)], 1);
        }
        perm[gn] = -1;
    }
    __syncthreads();
    if (tid < DBINS) dcur[tid] = dbin[tid];
    __syncthreads();
    for (int o = 1; o < DBINS; o <<= 1) {
        int v = 0;
        if (tid < DBINS && tid >= o) v = dcur[tid - o];
        __syncthreads();
        if (tid < DBINS) dcur[tid] += v;
        __syncthreads();
    }
    if (tid < DBINS) dcur[tid] -= dbin[tid];   // exclusive
    __syncthreads();
    if (tid < RB && gn < N) {
        const int r = atomicAdd(&dcur[min(cnt[tid], DBINS - 1)], 1);
        perm[b * RB + r] = gn;
    }
    __syncthreads();
    for (int i = s0 + tid; i < s1; i += 1024) {
        const u64 ed = edata1[i];
        const int d = ((u32)ed >> 20) & (RB - 1);
        const int p = atomicAdd(&cur[d], 1);
        edata2[(size_t)s0 + p] = ed;
    }
}

// ---------------------------------------------------------------------------
// agg64fused: per node n=perm[idx] (16 lanes/node):
//   acc = b1 + sum w_e * h1[src_e]   (register acc, bf16 gathers, unroll 8)
//   h2b[n] = bf16( relu(acc) @ W2 )  (shfl-broadcast mini-GEMM)
// ---------------------------------------------------------------------------
__global__ __launch_bounds__(256) void agg64fused_kernel(
    const u32* __restrict__ h1b, const u64* __restrict__ edata,
    const int* __restrict__ rowbeg, const int* __restrict__ rowend,
    const int* __restrict__ perm,
    const float* __restrict__ b1, const float* __restrict__ W2,
    u32* __restrict__ h2b, int NP) {
    __shared__ float w2t[16][68];        // W2 transposed [col][k]

    const int tid = threadIdx.x;
    for (int i = tid; i < 1024; i += 256)
        w2t[i & 15][i >> 4] = W2[i];
    __syncthreads();

    const int idx = blockIdx.x * 16 + (tid >> 4);
    if (idx >= NP) return;
    const int n = perm[idx];
    if (n < 0) return;
    const int f4 = tid & 15;

    float4 acc = *(const float4*)(b1 + 4 * f4);
    int i = rowbeg[n];
    const int end = rowend[n];

    for (; i + 8 <= end; i += 8) {
        u64 e[8];
        uint2 v[8];
        #pragma unroll
        for (int j = 0; j < 8; ++j) e[j] = edata[i + j];
        #pragma unroll
        for (int j = 0; j < 8; ++j)
            v[j] = *(const uint2*)(h1b + (size_t)((u32)e[j] & 0xFFFFF) * 32 + f4 * 2);
        #pragma unroll
        for (int j = 0; j < 8; ++j) {
            const float w = __uint_as_float((u32)(e[j] >> 32));
            acc.x += __uint_as_float(v[j].x << 16) * w;
            acc.y += __uint_as_float(v[j].x & 0xFFFF0000u) * w;
            acc.z += __uint_as_float(v[j].y << 16) * w;
            acc.w += __uint_as_float(v[j].y & 0xFFFF0000u) * w;
        }
    }
    if (i + 4 <= end) {
        u64 e[4];
        uint2 v[4];
        #pragma unroll
        for (int j = 0; j < 4; ++j) e[j] = edata[i + j];
        #pragma unroll
        for (int j = 0; j < 4; ++j)
            v[j] = *(const uint2*)(h1b + (size_t)((u32)e[j] & 0xFFFFF) * 32 + f4 * 2);
        #pragma unroll
        for (int j = 0; j < 4; ++j) {
            const float w = __uint_as_float((u32)(e[j] >> 32));
            acc.x += __uint_as_float(v[j].x << 16) * w;
            acc.y += __uint_as_float(v[j].x & 0xFFFF0000u) * w;
            acc.z += __uint_as_float(v[j].y << 16) * w;
            acc.w += __uint_as_float(v[j].y & 0xFFFF0000u) * w;
        }
        i += 4;
    }
    for (; i < end; ++i) {
        const u64 e0 = edata[i];
        const float w0 = __uint_as_float((u32)(e0 >> 32));
        const uint2 v0 = *(const uint2*)(h1b + (size_t)((u32)e0 & 0xFFFFF) * 32 + f4 * 2);
        acc.x += __uint_as_float(v0.x << 16) * w0;
        acc.y += __uint_as_float(v0.x & 0xFFFF0000u) * w0;
        acc.z += __uint_as_float(v0.y << 16) * w0;
        acc.w += __uint_as_float(v0.y & 0xFFFF0000u) * w0;
    }

    // mini-GEMM: o[c] = sum_k relu(acc_k) * W2[k][c], c = f4
    float racc[4] = {fmaxf(acc.x, 0.f), fmaxf(acc.y, 0.f),
                     fmaxf(acc.z, 0.f), fmaxf(acc.w, 0.f)};
    const int gb = (tid & 63) & 48;
    float o = 0.f;
    #pragma unroll
    for (int k4 = 0; k4 < 16; ++k4) {
        const float4 w4 = *(const float4*)(&w2t[f4][k4 * 4]);
        const float r0 = __shfl(racc[0], gb + k4, 64);
        const float r1 = __shfl(racc[1], gb + k4, 64);
        const float r2 = __shfl(racc[2], gb + k4, 64);
        const float r3 = __shfl(racc[3], gb + k4, 64);
        o += r0 * w4.x + r1 * w4.y + r2 * w4.z + r3 * w4.w;
    }
    const float o_hi = __shfl_down(o, 1, 64);
    if ((tid & 1) == 0) {
        h2b[(size_t)n * 8 + (f4 >> 1)] = pack2bf16(o, o_hi);
    }
}

// ---------------------------------------------------------------------------
// agg16: out[n] = b2 + sum w_e * h2b[src_e]  (2 lanes/node, bf16, unroll 8)
// ---------------------------------------------------------------------------
__global__ __launch_bounds__(256) void agg16_kernel(
    const u32* __restrict__ h2b, const u64* __restrict__ edata,
    const int* __restrict__ rowbeg, const int* __restrict__ rowend,
    const int* __restrict__ perm,
    const float* __restrict__ b2, float* __restrict__ out, int NP) {
    const int tid = threadIdx.x;
    const int idx = blockIdx.x * 128 + (tid >> 1);
    if (idx >= NP) return;
    const int n = perm[idx];
    if (n < 0) return;
    const int lane = tid & 1;            // feats lane*8 .. lane*8+7

    float acc[8];
    {
        const float4 ba = *(const float4*)(b2 + lane * 8);
        const float4 bb = *(const float4*)(b2 + lane * 8 + 4);
        acc[0] = ba.x; acc[1] = ba.y; acc[2] = ba.z; acc[3] = ba.w;
        acc[4] = bb.x; acc[5] = bb.y; acc[6] = bb.z; acc[7] = bb.w;
    }
    int i = rowbeg[n];
    const int end = rowend[n];

    for (; i + 8 <= end; i += 8) {
        u64 e[8];
        uint4 v[8];
        #pragma unroll
        for (int j = 0; j < 8; ++j) e[j] = edata[i + j];
        #pragma unroll
        for (int j = 0; j < 8; ++j)
            v[j] = *(const uint4*)(h2b + (size_t)((u32)e[j] & 0xFFFFF) * 8 + lane * 4);
        #pragma unroll
        for (int j = 0; j < 8; ++j) {
            const float w = __uint_as_float((u32)(e[j] >> 32));
            acc[0] += __uint_as_float(v[j].x << 16) * w;
            acc[1] += __uint_as_float(v[j].x & 0xFFFF0000u) * w;
            acc[2] += __uint_as_float(v[j].y << 16) * w;
            acc[3] += __uint_as_float(v[j].y & 0xFFFF0000u) * w;
            acc[4] += __uint_as_float(v[j].z << 16) * w;
            acc[5] += __uint_as_float(v[j].z & 0xFFFF0000u) * w;
            acc[6] += __uint_as_float(v[j].w << 16) * w;
            acc[7] += __uint_as_float(v[j].w & 0xFFFF0000u) * w;
        }
    }
    for (; i < end; ++i) {
        const u64 e0 = edata[i];
        const float w0 = __uint_as_float((u32)(e0 >> 32));
        const uint4 v0 = *(const uint4*)(h2b + (size_t)((u32)e0 & 0xFFFFF) * 8 + lane * 4);
        acc[0] += __uint_as_float(v0.x << 16) * w0;
        acc[1] += __uint_as_float(v0.x & 0xFFFF0000u) * w0;
        acc[2] += __uint_as_float(v0.y << 16) * w0;
        acc[3] += __uint_as_float(v0.y & 0xFFFF0000u) * w0;
        acc[4] += __uint_as_float(v0.z << 16) * w0;
        acc[5] += __uint_as_float(v0.z & 0xFFFF0000u) * w0;
        acc[6] += __uint_as_float(v0.w << 16) * w0;
        acc[7] += __uint_as_float(v0.w & 0xFFFF0000u) * w0;
    }
    float* p = out + (size_t)n * F_OUT + lane * 8;
    *(float4*)(p + 0) = make_float4(acc[0], acc[1], acc[2], acc[3]);
    *(float4*)(p + 4) = make_float4(acc[4], acc[5], acc[6], acc[7]);
}

extern "C" void kernel_launch(void* const* d_in, const int* in_sizes, int n_in,
                              void* d_out, int out_size, void* d_ws, size_t ws_size,
                              hipStream_t stream) {
    const float* x   = (const float*)d_in[0];
    const int*   src = (const int*)d_in[1];
    const int*   dst = (const int*)d_in[2];
    const float* ew  = (const float*)d_in[3];
    const float* W1  = (const float*)d_in[4];
    const float* b1  = (const float*)d_in[5];
    const float* W2  = (const float*)d_in[6];
    const float* b2  = (const float*)d_in[7];
    float* out = (float*)d_out;

    const int N = in_sizes[0] / F_IN;            // 100000
    const int E = in_sizes[1];                   // 1600000
    const int nbuck = (N + RB - 1) >> RB_SHIFT;  // 782
    const int NP = nbuck * RB;                   // padded node count (perm size)

    char* base = (char*)d_ws;
    auto align256 = [](size_t v) { return (v + 255) & ~(size_t)255; };
    size_t oH1   = 0;
    size_t oED1  = align256(oH1  + (size_t)N * 32 * 4);        // h1b bf16 12.8MB
    size_t oED2  = align256(oED1 + (size_t)nbuck * CAP * 8);   // edata1 19.2MB
    size_t oH2B  = align256(oED2 + (size_t)nbuck * CAP * 8);   // edata2 19.2MB
    size_t oRB   = align256(oH2B + (size_t)N * 8 * 4);         // h2b bf16 3.2MB
    size_t oRE   = align256(oRB  + (size_t)N * 4);
    size_t oPERM = align256(oRE  + (size_t)N * 4);
    size_t oCUR  = align256(oPERM + (size_t)NP * 4);
    (void)ws_size;

    u32*   h1b    = (u32*)(base + oH1);
    u64*   edata1 = (u64*)(base + oED1);
    u64*   edata2 = (u64*)(base + oED2);
    u32*   h2b    = (u32*)(base + oH2B);
    int*   rowbeg = (int*)(base + oRB);
    int*   rowend = (int*)(base + oRE);
    int*   perm   = (int*)(base + oPERM);
    int*   gcur   = (int*)(base + oCUR);

    // ---- preprocessing: CAP-strided bucket sort -> node sort + degree perm
    hipMemsetAsync(gcur, 0, (size_t)nbuck * 4, stream);
    fill_kernel<<<256, 1024, 0, stream>>>(src, dst, ew, gcur, edata1, E, nbuck);
    sort_kernel<<<nbuck, 1024, 0, stream>>>(edata1, gcur, edata2,
                                            rowbeg, rowend, perm, N);

    // ---- layer 1 transform
    gemm1_kernel<<<(N + 63) / 64, 256, 0, stream>>>(x, W1, h1b, N);
    // ---- layer-1 aggregate + relu + W2 (fused), h2 in bf16
    agg64fused_kernel<<<(NP + 15) / 16, 256, 0, stream>>>(
        h1b, edata2, rowbeg, rowend, perm, b1, W2, h2b, NP);
    // ---- layer-2 aggregate + bias
    agg16_kernel<<<(NP + 127) / 128, 256, 0, stream>>>(
        h2b, edata2, rowbeg, rowend, perm, b2, out, NP);
}